// Round 1
// baseline (237.055 us; speedup 1.0000x reference)
//
#include <hip/hip_runtime.h>

#define BATCH 4
#define SEQ   4096
#define DIM   1024
#define NCH   512
#define CHK   8
#define NROWS (BATCH*SEQ)

typedef __attribute__((ext_vector_type(4))) float f32x4;
typedef __attribute__((ext_vector_type(8))) short shortx8;
typedef __attribute__((ext_vector_type(4))) short shortx4;

static __device__ __forceinline__ unsigned short f2bf(float f){
    unsigned int u = __float_as_uint(f);
    u += 0x7FFFu + ((u >> 16) & 1u);
    return (unsigned short)(u >> 16);
}
static __device__ __forceinline__ float bf2f(unsigned short h){
    return __uint_as_float(((unsigned int)h) << 16);
}
static __device__ __forceinline__ float sigmoidf_fast(float x){
    return 1.0f / (1.0f + __expf(-x));
}
static __device__ __forceinline__ shortx4 pack4(f32x4 s){
    shortx4 o;
    o.x = (short)f2bf(s.x); o.y = (short)f2bf(s.y);
    o.z = (short)f2bf(s.z); o.w = (short)f2bf(s.w);
    return o;
}

// ---------------- K_pack: build interleaved bf16 weight matrix ----------------
// Wcat row n: grp=n>>5, r=n&31; r<16 -> Wr row grp*16+r (gate), else Wv row grp*16+r-16 (value)
__global__ __launch_bounds__(256) void k_pack_w(
    const float* __restrict__ Wr, const float* __restrict__ Wv,
    unsigned short* __restrict__ Wcat)
{
    const int n = blockIdx.x;
    const int grp = n >> 5, r = n & 31;
    const float* src = (r < 16) ? (Wr + (size_t)(grp*16 + r)*DIM)
                                : (Wv + (size_t)(grp*16 + (r-16))*DIM);
    const int tid = threadIdx.x;
    f32x4 v = reinterpret_cast<const f32x4*>(src)[tid];
    reinterpret_cast<shortx4*>(Wcat)[n*256 + tid] = pack4(v);
}

// ---------------- K1: shift + decay + exp + chunk-local scan ----------------
// one wave per chunk of 8 rows; lane owns d in {j*256 + lane*4 .. +3}, j=0..3
__global__ __launch_bounds__(256) void k_shift_scan(
    const float* __restrict__ X, const float* __restrict__ XP,
    const float* __restrict__ mu_p, const float* __restrict__ dw,
    const float* __restrict__ db_p,
    unsigned short* __restrict__ shifted,
    float* __restrict__ b_local, float* __restrict__ a_local,
    float* __restrict__ cumP)
{
    const int tid  = threadIdx.x;
    const int lane = tid & 63;
    const int wid  = tid >> 6;
    const int cid  = blockIdx.x*4 + wid;            // 0..2047
    const int batch = cid >> 9;
    const int chunk = cid & (NCH-1);
    const int row0  = batch*SEQ + chunk*CHK;

    const float mu = mu_p[0];
    const float om = 1.0f - mu;
    const float db = db_p[0];

    const f32x4* dwv = reinterpret_cast<const f32x4*>(dw);
    const f32x4 w0 = dwv[lane], w1 = dwv[64+lane], w2 = dwv[128+lane], w3 = dwv[192+lane];

    f32x4 b0 = {0,0,0,0}, b1 = {0,0,0,0}, b2 = {0,0,0,0}, b3 = {0,0,0,0};
    float a_run = 0.f, cp = 1.f;

    const f32x4* Xv  = reinterpret_cast<const f32x4*>(X);
    const f32x4* XPv = reinterpret_cast<const f32x4*>(XP);
    f32x4*  BL = reinterpret_cast<f32x4*>(b_local);
    shortx4* SH = reinterpret_cast<shortx4*>(shifted);

    for (int r = 0; r < CHK; ++r){
        const int row = row0 + r;
        const int rb  = row*(DIM/4);

        f32x4 x0 = Xv[rb+lane],     x1 = Xv[rb+64+lane],
              x2 = Xv[rb+128+lane], x3 = Xv[rb+192+lane];
        f32x4 p0 = XPv[rb+lane],     p1 = XPv[rb+64+lane],
              p2 = XPv[rb+128+lane], p3 = XPv[rb+192+lane];
        f32x4 s0 = mu*x0 + om*p0, s1 = mu*x1 + om*p1;
        f32x4 s2 = mu*x2 + om*p2, s3 = mu*x3 + om*p3;

        SH[rb+lane]     = pack4(s0);
        SH[rb+64+lane]  = pack4(s1);
        SH[rb+128+lane] = pack4(s2);
        SH[rb+192+lane] = pack4(s3);

        float dot = s0.x*w0.x + s0.y*w0.y + s0.z*w0.z + s0.w*w0.w
                  + s1.x*w1.x + s1.y*w1.y + s1.z*w1.z + s1.w*w1.w
                  + s2.x*w2.x + s2.y*w2.y + s2.z*w2.z + s2.w*w2.w
                  + s3.x*w3.x + s3.y*w3.y + s3.z*w3.z + s3.w*w3.w;

        f32x4 e0, e1, e2, e3;
        e0.x=__expf(s0.x); e0.y=__expf(s0.y); e0.z=__expf(s0.z); e0.w=__expf(s0.w);
        e1.x=__expf(s1.x); e1.y=__expf(s1.y); e1.z=__expf(s1.z); e1.w=__expf(s1.w);
        e2.x=__expf(s2.x); e2.y=__expf(s2.y); e2.z=__expf(s2.z); e2.w=__expf(s2.w);
        e3.x=__expf(s3.x); e3.y=__expf(s3.y); e3.z=__expf(s3.z); e3.w=__expf(s3.w);
        float ea = e0.x+e0.y+e0.z+e0.w + e1.x+e1.y+e1.z+e1.w
                 + e2.x+e2.y+e2.z+e2.w + e3.x+e3.y+e3.z+e3.w;

        #pragma unroll
        for (int off = 1; off < 64; off <<= 1){
            dot += __shfl_xor(dot, off, 64);
            ea  += __shfl_xor(ea,  off, 64);
        }

        const float dt = sigmoidf_fast(dot + db);
        a_run = dt*a_run + ea;
        cp   *= dt;
        b0 = dt*b0 + e0*s0;  b1 = dt*b1 + e1*s1;
        b2 = dt*b2 + e2*s2;  b3 = dt*b3 + e3*s3;

        BL[rb+lane]     = b0;
        BL[rb+64+lane]  = b1;
        BL[rb+128+lane] = b2;
        BL[rb+192+lane] = b3;
        if (lane == 0){ a_local[row] = a_run; cumP[row] = cp; }
    }
}

// ---------------- K2: sequential carry combine across chunks ----------------
// 16 blocks: batch = bid>>2, d-segment = bid&3 (256 d's each); 4-deep prefetch
__global__ __launch_bounds__(256) void k_combine(
    const float* __restrict__ b_local, const float* __restrict__ a_local,
    const float* __restrict__ cumP,
    float* __restrict__ carryA, float* __restrict__ carryB)
{
    const int batch = blockIdx.x >> 2;
    const int dseg  = blockIdx.x & 3;
    const int d = dseg*256 + threadIdx.x;

    __shared__ float sP[NCH], sA[NCH];
    for (int c = threadIdx.x; c < NCH; c += 256){
        const int er = batch*SEQ + c*CHK + (CHK-1);
        sP[c] = cumP[er];
        sA[c] = a_local[er];
    }
    __syncthreads();

    const float* bl = b_local + (size_t)batch*SEQ*DIM;
    float* cB = carryB + (size_t)batch*NCH*DIM;
    const bool wA = (dseg == 0 && threadIdx.x == 0);

    float cb = 0.f, ca = 0.f;
    float f0 = bl[(0*CHK+CHK-1)*DIM + d];
    float f1 = bl[(1*CHK+CHK-1)*DIM + d];
    float f2 = bl[(2*CHK+CHK-1)*DIM + d];
    float f3 = bl[(3*CHK+CHK-1)*DIM + d];

    for (int c = 0; c < NCH; c += 4){
        const float v0=f0, v1=f1, v2=f2, v3=f3;
        if (c+4 < NCH){
            f0 = bl[((c+4)*CHK+CHK-1)*DIM + d];
            f1 = bl[((c+5)*CHK+CHK-1)*DIM + d];
            f2 = bl[((c+6)*CHK+CHK-1)*DIM + d];
            f3 = bl[((c+7)*CHK+CHK-1)*DIM + d];
        }
        cB[(c+0)*DIM + d] = cb; if (wA) carryA[batch*NCH + c+0] = ca;
        cb = sP[c+0]*cb + v0;   ca = sP[c+0]*ca + sA[c+0];
        cB[(c+1)*DIM + d] = cb; if (wA) carryA[batch*NCH + c+1] = ca;
        cb = sP[c+1]*cb + v1;   ca = sP[c+1]*ca + sA[c+1];
        cB[(c+2)*DIM + d] = cb; if (wA) carryA[batch*NCH + c+2] = ca;
        cb = sP[c+2]*cb + v2;   ca = sP[c+2]*ca + sA[c+2];
        cB[(c+3)*DIM + d] = cb; if (wA) carryA[batch*NCH + c+3] = ca;
        cb = sP[c+3]*cb + v3;   ca = sP[c+3]*ca + sA[c+3];
    }
}

static __device__ __forceinline__ void block_reduce2(float& s, float& s2, float* red, int tid){
    #pragma unroll
    for (int off = 1; off < 64; off <<= 1){
        s  += __shfl_xor(s,  off, 64);
        s2 += __shfl_xor(s2, off, 64);
    }
    const int wid = tid >> 6, lane = tid & 63;
    if (lane == 0){ red[wid] = s; red[4+wid] = s2; }
    __syncthreads();
    s  = red[0]+red[1]+red[2]+red[3];
    s2 = red[4]+red[5]+red[6]+red[7];
}

// ---------------- K3: carry fixup + divide + LN1 -> merged (bf16) ----------------
__global__ __launch_bounds__(256) void k_fix_ln1(
    const float* __restrict__ b_local, const float* __restrict__ a_local,
    const float* __restrict__ cumP, const float* __restrict__ carryA,
    const float* __restrict__ carryB,
    const float* __restrict__ g1, const float* __restrict__ bb1,
    unsigned short* __restrict__ merged)
{
    const int row = blockIdx.x;
    const int batch = row >> 12;
    const int t = row & (SEQ-1);
    const int c = t >> 3;           // CHK = 8
    const int tid = threadIdx.x;

    const float cpv = cumP[row];
    const float a = a_local[row] + cpv * carryA[batch*NCH + c];
    const float inv_a = 1.0f / (a + 1e-8f);

    f32x4 bl = reinterpret_cast<const f32x4*>(b_local)[row*256 + tid];
    f32x4 cb = reinterpret_cast<const f32x4*>(carryB)[(batch*NCH + c)*256 + tid];
    f32x4 o = (bl + cpv*cb) * inv_a;

    float s  = o.x+o.y+o.z+o.w;
    float s2 = o.x*o.x + o.y*o.y + o.z*o.z + o.w*o.w;
    __shared__ float red[8];
    block_reduce2(s, s2, red, tid);

    const float mean = s * (1.0f/DIM);
    const float rstd = rsqrtf(s2*(1.0f/DIM) - mean*mean + 1e-5f);
    f32x4 gg = reinterpret_cast<const f32x4*>(g1)[tid];
    f32x4 bb = reinterpret_cast<const f32x4*>(bb1)[tid];
    f32x4 m = (o - mean)*rstd*gg + bb;
    reinterpret_cast<shortx4*>(merged)[row*256 + tid] = pack4(m);
}

// ---------------- K5: bf16 GEMM (m97 structure) + gate*value epilogue ----------------
typedef __attribute__((address_space(3))) unsigned int lds_uint;
typedef __attribute__((address_space(1))) unsigned int glob_uint;
static __device__ __forceinline__ void stage16(const unsigned short* g, unsigned short* l){
    __builtin_amdgcn_global_load_lds((const glob_uint*)g, (lds_uint*)l, 16, 0, 0);
}

__global__ __launch_bounds__(256) void k_gemm(
    const unsigned short* __restrict__ A,    // merged bf16 [16384][1024]
    const unsigned short* __restrict__ Bt,   // Wcat  bf16 [2048][1024]
    const float* __restrict__ rbias, const float* __restrict__ vbias,
    float* __restrict__ gv)
{
    __shared__ __align__(16) unsigned short As[128*32];
    __shared__ __align__(16) unsigned short Bs[128*32];
    const int tid  = threadIdx.x;
    const int lane = tid & 63;
    const int wid  = tid >> 6;
    const int nt = blockIdx.x & 15;
    const int mt = blockIdx.x >> 4;
    const int m0 = mt*128, n0 = nt*128;
    const int wr = wid >> 1, wc = wid & 1;

    f32x4 acc[4][4];
    #pragma unroll
    for (int i = 0; i < 4; ++i)
        #pragma unroll
        for (int j = 0; j < 4; ++j) acc[i][j] = (f32x4){0.f,0.f,0.f,0.f};

    const int srow = tid >> 2;
    const int scol = (tid & 3) << 3;
    const unsigned short* gA0 = A  + (size_t)(m0 + srow)*DIM + scol;
    const unsigned short* gA1 = A  + (size_t)(m0 + 64 + srow)*DIM + scol;
    const unsigned short* gB0 = Bt + (size_t)(n0 + srow)*DIM + scol;
    const unsigned short* gB1 = Bt + (size_t)(n0 + 64 + srow)*DIM + scol;
    unsigned short* lA0 = As + wid*512;
    unsigned short* lA1 = As + 2048 + wid*512;
    unsigned short* lB0 = Bs + wid*512;
    unsigned short* lB1 = Bs + 2048 + wid*512;

    const int fr = lane & 15, fq = lane >> 4;

    for (int kt = 0; kt < DIM/32; ++kt){
        __syncthreads();
        const int ko = kt*32;
        stage16(gA0 + ko, lA0);
        stage16(gA1 + ko, lA1);
        stage16(gB0 + ko, lB0);
        stage16(gB1 + ko, lB1);
        __syncthreads();

        shortx8 af[4], bfv[4];
        #pragma unroll
        for (int f = 0; f < 4; ++f){
            af[f]  = *reinterpret_cast<const shortx8*>(&As[(wr*64 + f*16 + fr)*32 + fq*8]);
            bfv[f] = *reinterpret_cast<const shortx8*>(&Bs[(wc*64 + f*16 + fr)*32 + fq*8]);
        }
        #pragma unroll
        for (int i = 0; i < 4; ++i)
            #pragma unroll
            for (int j = 0; j < 4; ++j)
                acc[i][j] = __builtin_amdgcn_mfma_f32_16x16x32_bf16(af[i], bfv[j], acc[i][j], 0, 0, 0);
    }

    // epilogue: fn even = gate cols, fn odd = value cols for same e-range
    #pragma unroll
    for (int p = 0; p < 2; ++p){
        const int e = (nt*4 + wc*2 + p)*16 + fr;
        const float rbe = rbias[e], vbe = vbias[e];
        #pragma unroll
        for (int i = 0; i < 4; ++i){
            f32x4 ga = acc[i][2*p], va = acc[i][2*p+1];
            const int mrow = m0 + wr*64 + i*16 + fq*4;
            #pragma unroll
            for (int q = 0; q < 4; ++q){
                const float gate = sigmoidf_fast(ga[q] + rbe);
                gv[(size_t)(mrow+q)*DIM + e] = gate * (va[q] + vbe);
            }
        }
    }
}

// ---------------- K6: LN2 + residual ----------------
__global__ __launch_bounds__(256) void k_ln2_res(
    const float* __restrict__ gvb, const unsigned short* __restrict__ shifted,
    const float* __restrict__ g2, const float* __restrict__ b2,
    float* __restrict__ out)
{
    const int row = blockIdx.x, tid = threadIdx.x;
    const int idx = row*256 + tid;
    f32x4 v = reinterpret_cast<const f32x4*>(gvb)[idx];
    float s  = v.x+v.y+v.z+v.w;
    float s2 = v.x*v.x + v.y*v.y + v.z*v.z + v.w*v.w;
    __shared__ float red[8];
    block_reduce2(s, s2, red, tid);
    const float mean = s * (1.0f/DIM);
    const float rstd = rsqrtf(s2*(1.0f/DIM) - mean*mean + 1e-5f);
    f32x4 gg = reinterpret_cast<const f32x4*>(g2)[tid];
    f32x4 bb = reinterpret_cast<const f32x4*>(b2)[tid];
    f32x4 nv = (v - mean)*rstd*gg + bb;
    shortx4 sh = reinterpret_cast<const shortx4*>(shifted)[idx];
    f32x4 o;
    o.x = bf2f((unsigned short)sh.x) + nv.x;
    o.y = bf2f((unsigned short)sh.y) + nv.y;
    o.z = bf2f((unsigned short)sh.z) + nv.z;
    o.w = bf2f((unsigned short)sh.w) + nv.w;
    reinterpret_cast<f32x4*>(out)[idx] = o;
}

extern "C" void kernel_launch(void* const* d_in, const int* in_sizes, int n_in,
                              void* d_out, int out_size, void* d_ws, size_t ws_size,
                              hipStream_t stream)
{
    (void)in_sizes; (void)n_in; (void)out_size; (void)ws_size;
    const float* x     = (const float*)d_in[0];
    const float* xprev = (const float*)d_in[1];
    const float* mu    = (const float*)d_in[2];
    const float* dw    = (const float*)d_in[3];
    const float* db    = (const float*)d_in[4];
    const float* ln1g  = (const float*)d_in[5];
    const float* ln1b  = (const float*)d_in[6];
    const float* Wr    = (const float*)d_in[7];
    const float* Wrb   = (const float*)d_in[8];
    const float* Wv    = (const float*)d_in[9];
    const float* Wvb   = (const float*)d_in[10];
    const float* ln2g  = (const float*)d_in[11];
    const float* ln2b  = (const float*)d_in[12];
    float* out = (float*)d_out;

    char* ws = (char*)d_ws;
    size_t off = 0;
    auto alloc = [&](size_t bytes) -> void* {
        void* p = ws + off;
        off += (bytes + 255) & ~(size_t)255;
        return p;
    };
    unsigned short* shifted = (unsigned short*)alloc((size_t)NROWS*DIM*2); // 33.5MB
    float* b_local          = (float*)alloc((size_t)NROWS*DIM*4);          // 67MB
    unsigned short* merged  = (unsigned short*)alloc((size_t)NROWS*DIM*2); // 33.5MB
    float* carryB           = (float*)alloc((size_t)BATCH*NCH*DIM*4);      // 8.4MB
    unsigned short* Wcat    = (unsigned short*)alloc((size_t)2048*1024*2); // 4MB
    float* a_local          = (float*)alloc((size_t)NROWS*4);
    float* cumP             = (float*)alloc((size_t)NROWS*4);
    float* carryA           = (float*)alloc((size_t)BATCH*NCH*4);
    float* gvbuf = b_local;  // b_local dead after k_fix_ln1 -> reuse for gv

    hipLaunchKernelGGL(k_pack_w,    dim3(2048),  dim3(256),  0, stream, Wr, Wv, Wcat);
    hipLaunchKernelGGL(k_shift_scan,dim3(512),   dim3(256),  0, stream,
                       x, xprev, mu, dw, db, shifted, b_local, a_local, cumP);
    hipLaunchKernelGGL(k_combine,   dim3(16),    dim3(256),  0, stream,
                       b_local, a_local, cumP, carryA, carryB);
    hipLaunchKernelGGL(k_fix_ln1,   dim3(16384), dim3(256),  0, stream,
                       b_local, a_local, cumP, carryA, carryB, ln1g, ln1b, merged);
    hipLaunchKernelGGL(k_gemm,      dim3(2048),  dim3(256),  0, stream,
                       merged, Wcat, Wrb, Wvb, gvbuf);
    hipLaunchKernelGGL(k_ln2_res,   dim3(16384), dim3(256),  0, stream,
                       gvbuf, shifted, ln2g, ln2b, out);
}

// Round 2
// 236.877 us; speedup vs baseline: 1.0008x; 1.0008x over previous
//
#include <hip/hip_runtime.h>

#define BATCH 4
#define SEQ   4096
#define DIM   1024
#define NCH   512
#define CHK   8
#define NROWS (BATCH*SEQ)
#define NT    16            // gemm K-tiles (1024/64)

typedef __attribute__((ext_vector_type(4))) float f32x4;
typedef __attribute__((ext_vector_type(8))) short shortx8;
typedef __attribute__((ext_vector_type(4))) short shortx4;

static __device__ __forceinline__ unsigned short f2bf(float f){
    unsigned int u = __float_as_uint(f);
    u += 0x7FFFu + ((u >> 16) & 1u);
    return (unsigned short)(u >> 16);
}
static __device__ __forceinline__ float bf2f(unsigned short h){
    return __uint_as_float(((unsigned int)h) << 16);
}
static __device__ __forceinline__ float sigmoidf_fast(float x){
    return 1.0f / (1.0f + __expf(-x));
}
static __device__ __forceinline__ shortx4 pack4(f32x4 s){
    shortx4 o;
    o.x = (short)f2bf(s.x); o.y = (short)f2bf(s.y);
    o.z = (short)f2bf(s.z); o.w = (short)f2bf(s.w);
    return o;
}
static __device__ __forceinline__ f32x4 unpack4(shortx4 s){
    f32x4 o;
    o.x = bf2f((unsigned short)s.x); o.y = bf2f((unsigned short)s.y);
    o.z = bf2f((unsigned short)s.z); o.w = bf2f((unsigned short)s.w);
    return o;
}

// ---------------- K_pack: interleaved bf16 weight matrix ----------------
// Wcat row n: grp=n>>5, r=n&31; r<16 -> Wr row grp*16+r (gate), else Wv (value)
__global__ __launch_bounds__(256) void k_pack_w(
    const float* __restrict__ Wr, const float* __restrict__ Wv,
    unsigned short* __restrict__ Wcat)
{
    const int n = blockIdx.x;
    const int grp = n >> 5, r = n & 31;
    const float* src = (r < 16) ? (Wr + (size_t)(grp*16 + r)*DIM)
                                : (Wv + (size_t)(grp*16 + (r-16))*DIM);
    const int tid = threadIdx.x;
    f32x4 v = reinterpret_cast<const f32x4*>(src)[tid];
    reinterpret_cast<shortx4*>(Wcat)[n*256 + tid] = pack4(v);
}

// ---------------- K1: shift + decay + exp + chunk-local scan ----------------
__global__ __launch_bounds__(256) void k_shift_scan(
    const float* __restrict__ X, const float* __restrict__ XP,
    const float* __restrict__ mu_p, const float* __restrict__ dw,
    const float* __restrict__ db_p,
    unsigned short* __restrict__ shifted,
    unsigned short* __restrict__ b_local, float* __restrict__ a_local,
    float* __restrict__ cumP)
{
    const int tid  = threadIdx.x;
    const int lane = tid & 63;
    const int wid  = tid >> 6;
    const int cid  = blockIdx.x*4 + wid;
    const int batch = cid >> 9;
    const int chunk = cid & (NCH-1);
    const int row0  = batch*SEQ + chunk*CHK;

    const float mu = mu_p[0];
    const float om = 1.0f - mu;
    const float db = db_p[0];

    const f32x4* dwv = reinterpret_cast<const f32x4*>(dw);
    const f32x4 w0 = dwv[lane], w1 = dwv[64+lane], w2 = dwv[128+lane], w3 = dwv[192+lane];

    f32x4 b0 = {0,0,0,0}, b1 = {0,0,0,0}, b2 = {0,0,0,0}, b3 = {0,0,0,0};
    float a_run = 0.f, cp = 1.f;

    const f32x4* Xv  = reinterpret_cast<const f32x4*>(X);
    const f32x4* XPv = reinterpret_cast<const f32x4*>(XP);
    shortx4* BL = reinterpret_cast<shortx4*>(b_local);
    shortx4* SH = reinterpret_cast<shortx4*>(shifted);

    for (int r = 0; r < CHK; ++r){
        const int row = row0 + r;
        const int rb  = row*(DIM/4);

        f32x4 x0 = Xv[rb+lane],     x1 = Xv[rb+64+lane],
              x2 = Xv[rb+128+lane], x3 = Xv[rb+192+lane];
        f32x4 p0 = XPv[rb+lane],     p1 = XPv[rb+64+lane],
              p2 = XPv[rb+128+lane], p3 = XPv[rb+192+lane];
        f32x4 s0 = mu*x0 + om*p0, s1 = mu*x1 + om*p1;
        f32x4 s2 = mu*x2 + om*p2, s3 = mu*x3 + om*p3;

        SH[rb+lane]     = pack4(s0);
        SH[rb+64+lane]  = pack4(s1);
        SH[rb+128+lane] = pack4(s2);
        SH[rb+192+lane] = pack4(s3);

        float dot = s0.x*w0.x + s0.y*w0.y + s0.z*w0.z + s0.w*w0.w
                  + s1.x*w1.x + s1.y*w1.y + s1.z*w1.z + s1.w*w1.w
                  + s2.x*w2.x + s2.y*w2.y + s2.z*w2.z + s2.w*w2.w
                  + s3.x*w3.x + s3.y*w3.y + s3.z*w3.z + s3.w*w3.w;

        f32x4 e0, e1, e2, e3;
        e0.x=__expf(s0.x); e0.y=__expf(s0.y); e0.z=__expf(s0.z); e0.w=__expf(s0.w);
        e1.x=__expf(s1.x); e1.y=__expf(s1.y); e1.z=__expf(s1.z); e1.w=__expf(s1.w);
        e2.x=__expf(s2.x); e2.y=__expf(s2.y); e2.z=__expf(s2.z); e2.w=__expf(s2.w);
        e3.x=__expf(s3.x); e3.y=__expf(s3.y); e3.z=__expf(s3.z); e3.w=__expf(s3.w);
        float ea = e0.x+e0.y+e0.z+e0.w + e1.x+e1.y+e1.z+e1.w
                 + e2.x+e2.y+e2.z+e2.w + e3.x+e3.y+e3.z+e3.w;

        #pragma unroll
        for (int off = 1; off < 64; off <<= 1){
            dot += __shfl_xor(dot, off, 64);
            ea  += __shfl_xor(ea,  off, 64);
        }

        const float dt = sigmoidf_fast(dot + db);
        a_run = dt*a_run + ea;
        cp   *= dt;
        b0 = dt*b0 + e0*s0;  b1 = dt*b1 + e1*s1;
        b2 = dt*b2 + e2*s2;  b3 = dt*b3 + e3*s3;

        BL[rb+lane]     = pack4(b0);
        BL[rb+64+lane]  = pack4(b1);
        BL[rb+128+lane] = pack4(b2);
        BL[rb+192+lane] = pack4(b3);
        if (lane == 0){ a_local[row] = a_run; cumP[row] = cp; }
    }
}

// ---------------- K2: sequential carry combine across chunks ----------------
__global__ __launch_bounds__(256) void k_combine(
    const unsigned short* __restrict__ b_local, const float* __restrict__ a_local,
    const float* __restrict__ cumP,
    float* __restrict__ carryA, unsigned short* __restrict__ carryB)
{
    const int batch = blockIdx.x >> 2;
    const int dseg  = blockIdx.x & 3;
    const int d = dseg*256 + threadIdx.x;

    __shared__ float sP[NCH], sA[NCH];
    for (int c = threadIdx.x; c < NCH; c += 256){
        const int er = batch*SEQ + c*CHK + (CHK-1);
        sP[c] = cumP[er];
        sA[c] = a_local[er];
    }
    __syncthreads();

    const unsigned short* bl = b_local + (size_t)batch*SEQ*DIM;
    unsigned short* cB = carryB + (size_t)batch*NCH*DIM;
    const bool wA = (dseg == 0 && threadIdx.x == 0);

    float cb = 0.f, ca = 0.f;
    float f0 = bf2f(bl[(0*CHK+CHK-1)*DIM + d]);
    float f1 = bf2f(bl[(1*CHK+CHK-1)*DIM + d]);
    float f2 = bf2f(bl[(2*CHK+CHK-1)*DIM + d]);
    float f3 = bf2f(bl[(3*CHK+CHK-1)*DIM + d]);

    for (int c = 0; c < NCH; c += 4){
        const float v0=f0, v1=f1, v2=f2, v3=f3;
        if (c+4 < NCH){
            f0 = bf2f(bl[((c+4)*CHK+CHK-1)*DIM + d]);
            f1 = bf2f(bl[((c+5)*CHK+CHK-1)*DIM + d]);
            f2 = bf2f(bl[((c+6)*CHK+CHK-1)*DIM + d]);
            f3 = bf2f(bl[((c+7)*CHK+CHK-1)*DIM + d]);
        }
        cB[(c+0)*DIM + d] = f2bf(cb); if (wA) carryA[batch*NCH + c+0] = ca;
        cb = sP[c+0]*cb + v0;   ca = sP[c+0]*ca + sA[c+0];
        cB[(c+1)*DIM + d] = f2bf(cb); if (wA) carryA[batch*NCH + c+1] = ca;
        cb = sP[c+1]*cb + v1;   ca = sP[c+1]*ca + sA[c+1];
        cB[(c+2)*DIM + d] = f2bf(cb); if (wA) carryA[batch*NCH + c+2] = ca;
        cb = sP[c+2]*cb + v2;   ca = sP[c+2]*ca + sA[c+2];
        cB[(c+3)*DIM + d] = f2bf(cb); if (wA) carryA[batch*NCH + c+3] = ca;
        cb = sP[c+3]*cb + v3;   ca = sP[c+3]*ca + sA[c+3];
    }
}

static __device__ __forceinline__ void block_reduce2(float& s, float& s2, float* red, int tid){
    #pragma unroll
    for (int off = 1; off < 64; off <<= 1){
        s  += __shfl_xor(s,  off, 64);
        s2 += __shfl_xor(s2, off, 64);
    }
    const int wid = tid >> 6, lane = tid & 63;
    if (lane == 0){ red[wid] = s; red[4+wid] = s2; }
    __syncthreads();
    s  = red[0]+red[1]+red[2]+red[3];
    s2 = red[4]+red[5]+red[6]+red[7];
}

// ---------------- K3: carry fixup + divide + LN1 -> merged (bf16) ----------------
__global__ __launch_bounds__(256) void k_fix_ln1(
    const unsigned short* __restrict__ b_local, const float* __restrict__ a_local,
    const float* __restrict__ cumP, const float* __restrict__ carryA,
    const unsigned short* __restrict__ carryB,
    const float* __restrict__ g1, const float* __restrict__ bb1,
    unsigned short* __restrict__ merged)
{
    const int row = blockIdx.x;
    const int batch = row >> 12;
    const int t = row & (SEQ-1);
    const int c = t >> 3;
    const int tid = threadIdx.x;

    const float cpv = cumP[row];
    const float a = a_local[row] + cpv * carryA[batch*NCH + c];
    const float inv_a = 1.0f / (a + 1e-8f);

    f32x4 bl = unpack4(reinterpret_cast<const shortx4*>(b_local)[row*256 + tid]);
    f32x4 cb = unpack4(reinterpret_cast<const shortx4*>(carryB)[(batch*NCH + c)*256 + tid]);
    f32x4 o = (bl + cpv*cb) * inv_a;

    float s  = o.x+o.y+o.z+o.w;
    float s2 = o.x*o.x + o.y*o.y + o.z*o.z + o.w*o.w;
    __shared__ float red[8];
    block_reduce2(s, s2, red, tid);

    const float mean = s * (1.0f/DIM);
    const float rstd = rsqrtf(s2*(1.0f/DIM) - mean*mean + 1e-5f);
    f32x4 gg = reinterpret_cast<const f32x4*>(g1)[tid];
    f32x4 bb = reinterpret_cast<const f32x4*>(bb1)[tid];
    f32x4 m = (o - mean)*rstd*gg + bb;
    reinterpret_cast<shortx4*>(merged)[row*256 + tid] = pack4(m);
}

// ---------------- K5: deep-pipelined bf16 GEMM (ring-3, counted vmcnt) ------
// BM=256, BN=128 (Bt rows), BK=64. 8 waves (2m x 4n). Per-wave C: 128x32.
// LDS per buf: A 32KB (2 HT) + B 16KB (1 HT) = 48KB; 3 bufs = 144KB.
// HT = 128x64 bf16 as 16 subtiles (16rows x 32cols, 1024B), swizzle:
//   col-group (8 cols) ^= 2 when (row&8)  -- applied on global src & ds_read.
typedef __attribute__((address_space(3))) unsigned int lds_uint;
typedef __attribute__((address_space(1))) unsigned int glob_uint;
static __device__ __forceinline__ void gload16(const unsigned short* g, char* l){
    __builtin_amdgcn_global_load_lds((const glob_uint*)g, (lds_uint*)l, 16, 0, 0);
}
#define SBAR() do { __builtin_amdgcn_sched_barrier(0); __builtin_amdgcn_s_barrier(); __builtin_amdgcn_sched_barrier(0); } while(0)

__global__ __launch_bounds__(512, 2) void k_gemm(
    const unsigned short* __restrict__ A,    // merged bf16 [16384][1024]
    const unsigned short* __restrict__ Bt,   // Wcat  bf16 [2048][1024]
    const float* __restrict__ rbias, const float* __restrict__ vbias,
    unsigned short* __restrict__ gv)         // bf16 [16384][1024]
{
    __shared__ __align__(16) char lds[3*49152];
    const int tid  = threadIdx.x;
    const int lane = tid & 63;
    const int wid  = tid >> 6;       // 0..7
    const int wm   = wid >> 2;       // 0..1
    const int wn   = wid & 3;        // 0..3

    // bijective XCD swizzle (nwg=1024, %8==0), nt-inner for A-panel L2 reuse
    const int bid  = blockIdx.x;
    const int wgid = (bid & 7)*128 + (bid >> 3);
    const int mt = wgid >> 4, nt = wgid & 15;
    const int m0 = mt*256, n0 = nt*128;

    // ---- staging source (pre-swizzled col-group) ----
    const int sr  = lane >> 2;                                  // row in subtile
    const int scg = (lane & 3) ^ (((lane >> 5) & 1) << 1);      // swizzled col-grp
    const unsigned short* gA = A  + (size_t)(m0 + wid*16 + sr)*DIM + scg*8;
    const unsigned short* gB = Bt + (size_t)(n0 + wid*16 + sr)*DIM + scg*8;

    // ---- fragment read offset (with matching swizzle) ----
    const int fr = lane & 15, fq = lane >> 4;
    const int soff = fr*64 + ((fq*16) ^ ((fr & 8) ? 32 : 0));

    f32x4 acc[8][2];
    #pragma unroll
    for (int i = 0; i < 8; ++i){ acc[i][0] = (f32x4){0,0,0,0}; acc[i][1] = (f32x4){0,0,0,0}; }

    auto STAGE_A = [&](int buf, int tk){   // 4 loads: A half0+half1, kb0+kb1
        char* dst = &lds[buf*49152 + wid*2048];
        const unsigned short* src = gA + tk*64;
        gload16(src,             dst);
        gload16(src + 32,        dst + 1024);
        gload16(src + 128*DIM,      dst + 16384);
        gload16(src + 128*DIM + 32, dst + 16384 + 1024);
    };
    auto STAGE_B = [&](int buf, int tk){   // 2 loads
        char* dst = &lds[buf*49152 + 32768 + wid*2048];
        const unsigned short* src = gB + tk*64;
        gload16(src,      dst);
        gload16(src + 32, dst + 1024);
    };

    // prologue: tiles 0 and 1
    STAGE_A(0, 0); STAGE_B(0, 0);
    STAGE_A(1, 1); STAGE_B(1, 1);
    asm volatile("s_waitcnt vmcnt(6)" ::: "memory");
    SBAR();

    int bc = 0, bn = 2;
    for (int t = 0; t < NT; ++t){
        const char* bufA = &lds[bc*49152];
        const char* bufB = bufA + 32768;

        // ---- phase 0: B frags + A frags mf0..3, stage A(t+2) ----
        shortx8 bq[2][2], af[4][2];
        #pragma unroll
        for (int nf = 0; nf < 2; ++nf)
            #pragma unroll
            for (int ks = 0; ks < 2; ++ks)
                bq[nf][ks] = *reinterpret_cast<const shortx8*>(bufB + ((wn*2+nf)*2+ks)*1024 + soff);
        #pragma unroll
        for (int mf = 0; mf < 4; ++mf)
            #pragma unroll
            for (int ks = 0; ks < 2; ++ks)
                af[mf][ks] = *reinterpret_cast<const shortx8*>(bufA + wm*16384 + (mf*2+ks)*1024 + soff);
        if (t < NT-2) STAGE_A(bn, t+2);
        SBAR();
        __builtin_amdgcn_s_setprio(1);
        #pragma unroll
        for (int mf = 0; mf < 4; ++mf)
            #pragma unroll
            for (int nf = 0; nf < 2; ++nf){
                acc[mf][nf] = __builtin_amdgcn_mfma_f32_16x16x32_bf16(af[mf][0], bq[nf][0], acc[mf][nf], 0,0,0);
                acc[mf][nf] = __builtin_amdgcn_mfma_f32_16x16x32_bf16(af[mf][1], bq[nf][1], acc[mf][nf], 0,0,0);
            }
        __builtin_amdgcn_s_setprio(0);
        SBAR();

        // ---- phase 1: A frags mf4..7, stage B(t+2), counted vmcnt ----
        #pragma unroll
        for (int mf = 0; mf < 4; ++mf)
            #pragma unroll
            for (int ks = 0; ks < 2; ++ks)
                af[mf][ks] = *reinterpret_cast<const shortx8*>(bufA + wm*16384 + ((mf+4)*2+ks)*1024 + soff);
        if (t < NT-2){
            STAGE_B(bn, t+2);
            asm volatile("s_waitcnt vmcnt(6)" ::: "memory");
        } else {
            asm volatile("s_waitcnt vmcnt(0)" ::: "memory");
        }
        SBAR();
        __builtin_amdgcn_s_setprio(1);
        #pragma unroll
        for (int mf = 0; mf < 4; ++mf)
            #pragma unroll
            for (int nf = 0; nf < 2; ++nf){
                acc[mf+4][nf] = __builtin_amdgcn_mfma_f32_16x16x32_bf16(af[mf][0], bq[nf][0], acc[mf+4][nf], 0,0,0);
                acc[mf+4][nf] = __builtin_amdgcn_mfma_f32_16x16x32_bf16(af[mf][1], bq[nf][1], acc[mf+4][nf], 0,0,0);
            }
        __builtin_amdgcn_s_setprio(0);
        SBAR();

        bc = (bc == 2) ? 0 : bc+1;
        bn = (bn == 2) ? 0 : bn+1;
    }

    // ---- epilogue: sigmoid(gate)*value -> LDS transpose -> coalesced store --
    __syncthreads();
    unsigned short* ep = reinterpret_cast<unsigned short*>(lds);  // [256][64]
    const int e = (nt*4 + wn)*16 + fr;
    const float rbe = rbias[e], vbe = vbias[e];
    #pragma unroll
    for (int mf = 0; mf < 8; ++mf){
        const int rbase = wm*128 + mf*16 + fq*4;
        #pragma unroll
        for (int q = 0; q < 4; ++q){
            const float g = sigmoidf_fast(acc[mf][0][q] + rbe);
            const float v = acc[mf][1][q] + vbe;
            ep[(rbase + q)*64 + wn*16 + fr] = f2bf(g*v);
        }
    }
    __syncthreads();
    #pragma unroll
    for (int p = 0; p < 4; ++p){
        const int row = p*64 + (tid >> 3);
        const int cg8 = tid & 7;
        shortx8 val = *reinterpret_cast<const shortx8*>(&ep[row*64 + cg8*8]);
        *reinterpret_cast<shortx8*>(&gv[(size_t)(m0+row)*DIM + nt*64 + cg8*8]) = val;
    }
}

// ---------------- K6: LN2 + residual ----------------
__global__ __launch_bounds__(256) void k_ln2_res(
    const unsigned short* __restrict__ gvb, const unsigned short* __restrict__ shifted,
    const float* __restrict__ g2, const float* __restrict__ b2,
    float* __restrict__ out)
{
    const int row = blockIdx.x, tid = threadIdx.x;
    const int idx = row*256 + tid;
    f32x4 v = unpack4(reinterpret_cast<const shortx4*>(gvb)[idx]);
    float s  = v.x+v.y+v.z+v.w;
    float s2 = v.x*v.x + v.y*v.y + v.z*v.z + v.w*v.w;
    __shared__ float red[8];
    block_reduce2(s, s2, red, tid);
    const float mean = s * (1.0f/DIM);
    const float rstd = rsqrtf(s2*(1.0f/DIM) - mean*mean + 1e-5f);
    f32x4 gg = reinterpret_cast<const f32x4*>(g2)[tid];
    f32x4 bb = reinterpret_cast<const f32x4*>(b2)[tid];
    f32x4 nv = (v - mean)*rstd*gg + bb;
    f32x4 sh = unpack4(reinterpret_cast<const shortx4*>(shifted)[idx]);
    reinterpret_cast<f32x4*>(out)[idx] = sh + nv;
}

extern "C" void kernel_launch(void* const* d_in, const int* in_sizes, int n_in,
                              void* d_out, int out_size, void* d_ws, size_t ws_size,
                              hipStream_t stream)
{
    (void)in_sizes; (void)n_in; (void)out_size; (void)ws_size;
    const float* x     = (const float*)d_in[0];
    const float* xprev = (const float*)d_in[1];
    const float* mu    = (const float*)d_in[2];
    const float* dw    = (const float*)d_in[3];
    const float* db    = (const float*)d_in[4];
    const float* ln1g  = (const float*)d_in[5];
    const float* ln1b  = (const float*)d_in[6];
    const float* Wr    = (const float*)d_in[7];
    const float* Wrb   = (const float*)d_in[8];
    const float* Wv    = (const float*)d_in[9];
    const float* Wvb   = (const float*)d_in[10];
    const float* ln2g  = (const float*)d_in[11];
    const float* ln2b  = (const float*)d_in[12];
    float* out = (float*)d_out;

    char* ws = (char*)d_ws;
    size_t off = 0;
    auto alloc = [&](size_t bytes) -> void* {
        void* p = ws + off;
        off += (bytes + 255) & ~(size_t)255;
        return p;
    };
    unsigned short* shifted = (unsigned short*)alloc((size_t)NROWS*DIM*2);
    unsigned short* b_local = (unsigned short*)alloc((size_t)NROWS*DIM*2);
    unsigned short* merged  = (unsigned short*)alloc((size_t)NROWS*DIM*2);
    unsigned short* carryB  = (unsigned short*)alloc((size_t)BATCH*NCH*DIM*2);
    unsigned short* Wcat    = (unsigned short*)alloc((size_t)2048*1024*2);
    float* a_local          = (float*)alloc((size_t)NROWS*4);
    float* cumP             = (float*)alloc((size_t)NROWS*4);
    float* carryA           = (float*)alloc((size_t)BATCH*NCH*4);
    unsigned short* gvbuf   = b_local;   // b_local dead after k_fix_ln1

    hipLaunchKernelGGL(k_pack_w,    dim3(2048),  dim3(256), 0, stream, Wr, Wv, Wcat);
    hipLaunchKernelGGL(k_shift_scan,dim3(512),   dim3(256), 0, stream,
                       x, xprev, mu, dw, db, shifted, b_local, a_local, cumP);
    hipLaunchKernelGGL(k_combine,   dim3(16),    dim3(256), 0, stream,
                       b_local, a_local, cumP, carryA, carryB);
    hipLaunchKernelGGL(k_fix_ln1,   dim3(16384), dim3(256), 0, stream,
                       b_local, a_local, cumP, carryA, carryB, ln1g, ln1b, merged);
    hipLaunchKernelGGL(k_gemm,      dim3(1024),  dim3(512), 0, stream,
                       merged, Wcat, Wrb, Wvb, gvbuf);
    hipLaunchKernelGGL(k_ln2_res,   dim3(16384), dim3(256), 0, stream,
                       gvbuf, shifted, ln2g, ln2b, out);
}

// Round 3
// 230.790 us; speedup vs baseline: 1.0271x; 1.0264x over previous
//
#include <hip/hip_runtime.h>

#define BATCH 4
#define SEQ   4096
#define DIM   1024
#define NCH   512
#define CHK   8
#define NROWS (BATCH*SEQ)
#define NKT   32            // gemm K-tiles (1024/32)

typedef __attribute__((ext_vector_type(4))) float f32x4;
typedef __attribute__((ext_vector_type(8))) short shortx8;
typedef __attribute__((ext_vector_type(4))) short shortx4;

static __device__ __forceinline__ unsigned short f2bf(float f){
    unsigned int u = __float_as_uint(f);
    u += 0x7FFFu + ((u >> 16) & 1u);
    return (unsigned short)(u >> 16);
}
static __device__ __forceinline__ float bf2f(unsigned short h){
    return __uint_as_float(((unsigned int)h) << 16);
}
static __device__ __forceinline__ float sigmoidf_fast(float x){
    return 1.0f / (1.0f + __expf(-x));
}
static __device__ __forceinline__ shortx4 pack4(f32x4 s){
    shortx4 o;
    o.x = (short)f2bf(s.x); o.y = (short)f2bf(s.y);
    o.z = (short)f2bf(s.z); o.w = (short)f2bf(s.w);
    return o;
}
static __device__ __forceinline__ f32x4 unpack4(shortx4 s){
    f32x4 o;
    o.x = bf2f((unsigned short)s.x); o.y = bf2f((unsigned short)s.y);
    o.z = bf2f((unsigned short)s.z); o.w = bf2f((unsigned short)s.w);
    return o;
}

// ---------------- K_pack: interleaved bf16 weight matrix ----------------
__global__ __launch_bounds__(256) void k_pack_w(
    const float* __restrict__ Wr, const float* __restrict__ Wv,
    unsigned short* __restrict__ Wcat)
{
    const int n = blockIdx.x;
    const int grp = n >> 5, r = n & 31;
    const float* src = (r < 16) ? (Wr + (size_t)(grp*16 + r)*DIM)
                                : (Wv + (size_t)(grp*16 + (r-16))*DIM);
    const int tid = threadIdx.x;
    f32x4 v = reinterpret_cast<const f32x4*>(src)[tid];
    reinterpret_cast<shortx4*>(Wcat)[n*256 + tid] = pack4(v);
}

// ---------------- K1: shift + decay + exp + chunk-local scan ----------------
__global__ __launch_bounds__(256) void k_shift_scan(
    const float* __restrict__ X, const float* __restrict__ XP,
    const float* __restrict__ mu_p, const float* __restrict__ dw,
    const float* __restrict__ db_p,
    unsigned short* __restrict__ shifted,
    unsigned short* __restrict__ b_local, float* __restrict__ a_local,
    float* __restrict__ cumP)
{
    const int tid  = threadIdx.x;
    const int lane = tid & 63;
    const int wid  = tid >> 6;
    const int cid  = blockIdx.x*4 + wid;
    const int batch = cid >> 9;
    const int chunk = cid & (NCH-1);
    const int row0  = batch*SEQ + chunk*CHK;

    const float mu = mu_p[0];
    const float om = 1.0f - mu;
    const float db = db_p[0];

    const f32x4* dwv = reinterpret_cast<const f32x4*>(dw);
    const f32x4 w0 = dwv[lane], w1 = dwv[64+lane], w2 = dwv[128+lane], w3 = dwv[192+lane];

    f32x4 b0 = {0,0,0,0}, b1 = {0,0,0,0}, b2 = {0,0,0,0}, b3 = {0,0,0,0};
    float a_run = 0.f, cp = 1.f;

    const f32x4* Xv  = reinterpret_cast<const f32x4*>(X);
    const f32x4* XPv = reinterpret_cast<const f32x4*>(XP);
    shortx4* BL = reinterpret_cast<shortx4*>(b_local);
    shortx4* SH = reinterpret_cast<shortx4*>(shifted);

    for (int r = 0; r < CHK; ++r){
        const int row = row0 + r;
        const int rb  = row*(DIM/4);

        f32x4 x0 = Xv[rb+lane],     x1 = Xv[rb+64+lane],
              x2 = Xv[rb+128+lane], x3 = Xv[rb+192+lane];
        f32x4 p0 = XPv[rb+lane],     p1 = XPv[rb+64+lane],
              p2 = XPv[rb+128+lane], p3 = XPv[rb+192+lane];
        f32x4 s0 = mu*x0 + om*p0, s1 = mu*x1 + om*p1;
        f32x4 s2 = mu*x2 + om*p2, s3 = mu*x3 + om*p3;

        SH[rb+lane]     = pack4(s0);
        SH[rb+64+lane]  = pack4(s1);
        SH[rb+128+lane] = pack4(s2);
        SH[rb+192+lane] = pack4(s3);

        float dot = s0.x*w0.x + s0.y*w0.y + s0.z*w0.z + s0.w*w0.w
                  + s1.x*w1.x + s1.y*w1.y + s1.z*w1.z + s1.w*w1.w
                  + s2.x*w2.x + s2.y*w2.y + s2.z*w2.z + s2.w*w2.w
                  + s3.x*w3.x + s3.y*w3.y + s3.z*w3.z + s3.w*w3.w;

        f32x4 e0, e1, e2, e3;
        e0.x=__expf(s0.x); e0.y=__expf(s0.y); e0.z=__expf(s0.z); e0.w=__expf(s0.w);
        e1.x=__expf(s1.x); e1.y=__expf(s1.y); e1.z=__expf(s1.z); e1.w=__expf(s1.w);
        e2.x=__expf(s2.x); e2.y=__expf(s2.y); e2.z=__expf(s2.z); e2.w=__expf(s2.w);
        e3.x=__expf(s3.x); e3.y=__expf(s3.y); e3.z=__expf(s3.z); e3.w=__expf(s3.w);
        float ea = e0.x+e0.y+e0.z+e0.w + e1.x+e1.y+e1.z+e1.w
                 + e2.x+e2.y+e2.z+e2.w + e3.x+e3.y+e3.z+e3.w;

        #pragma unroll
        for (int off = 1; off < 64; off <<= 1){
            dot += __shfl_xor(dot, off, 64);
            ea  += __shfl_xor(ea,  off, 64);
        }

        const float dt = sigmoidf_fast(dot + db);
        a_run = dt*a_run + ea;
        cp   *= dt;
        b0 = dt*b0 + e0*s0;  b1 = dt*b1 + e1*s1;
        b2 = dt*b2 + e2*s2;  b3 = dt*b3 + e3*s3;

        BL[rb+lane]     = pack4(b0);
        BL[rb+64+lane]  = pack4(b1);
        BL[rb+128+lane] = pack4(b2);
        BL[rb+192+lane] = pack4(b3);
        if (lane == 0){ a_local[row] = a_run; cumP[row] = cp; }
    }
}

// ---------------- K2: sequential carry combine across chunks ----------------
__global__ __launch_bounds__(256) void k_combine(
    const unsigned short* __restrict__ b_local, const float* __restrict__ a_local,
    const float* __restrict__ cumP,
    float* __restrict__ carryA, unsigned short* __restrict__ carryB)
{
    const int batch = blockIdx.x >> 2;
    const int dseg  = blockIdx.x & 3;
    const int d = dseg*256 + threadIdx.x;

    __shared__ float sP[NCH], sA[NCH];
    for (int c = threadIdx.x; c < NCH; c += 256){
        const int er = batch*SEQ + c*CHK + (CHK-1);
        sP[c] = cumP[er];
        sA[c] = a_local[er];
    }
    __syncthreads();

    const unsigned short* bl = b_local + (size_t)batch*SEQ*DIM;
    unsigned short* cB = carryB + (size_t)batch*NCH*DIM;
    const bool wA = (dseg == 0 && threadIdx.x == 0);

    float cb = 0.f, ca = 0.f;
    float f0 = bf2f(bl[(0*CHK+CHK-1)*DIM + d]);
    float f1 = bf2f(bl[(1*CHK+CHK-1)*DIM + d]);
    float f2 = bf2f(bl[(2*CHK+CHK-1)*DIM + d]);
    float f3 = bf2f(bl[(3*CHK+CHK-1)*DIM + d]);

    for (int c = 0; c < NCH; c += 4){
        const float v0=f0, v1=f1, v2=f2, v3=f3;
        if (c+4 < NCH){
            f0 = bf2f(bl[((c+4)*CHK+CHK-1)*DIM + d]);
            f1 = bf2f(bl[((c+5)*CHK+CHK-1)*DIM + d]);
            f2 = bf2f(bl[((c+6)*CHK+CHK-1)*DIM + d]);
            f3 = bf2f(bl[((c+7)*CHK+CHK-1)*DIM + d]);
        }
        cB[(c+0)*DIM + d] = f2bf(cb); if (wA) carryA[batch*NCH + c+0] = ca;
        cb = sP[c+0]*cb + v0;   ca = sP[c+0]*ca + sA[c+0];
        cB[(c+1)*DIM + d] = f2bf(cb); if (wA) carryA[batch*NCH + c+1] = ca;
        cb = sP[c+1]*cb + v1;   ca = sP[c+1]*ca + sA[c+1];
        cB[(c+2)*DIM + d] = f2bf(cb); if (wA) carryA[batch*NCH + c+2] = ca;
        cb = sP[c+2]*cb + v2;   ca = sP[c+2]*ca + sA[c+2];
        cB[(c+3)*DIM + d] = f2bf(cb); if (wA) carryA[batch*NCH + c+3] = ca;
        cb = sP[c+3]*cb + v3;   ca = sP[c+3]*ca + sA[c+3];
    }
}

static __device__ __forceinline__ void block_reduce2(float& s, float& s2, float* red, int tid){
    #pragma unroll
    for (int off = 1; off < 64; off <<= 1){
        s  += __shfl_xor(s,  off, 64);
        s2 += __shfl_xor(s2, off, 64);
    }
    const int wid = tid >> 6, lane = tid & 63;
    if (lane == 0){ red[wid] = s; red[4+wid] = s2; }
    __syncthreads();
    s  = red[0]+red[1]+red[2]+red[3];
    s2 = red[4]+red[5]+red[6]+red[7];
}

// ---------------- K3: carry fixup + divide + LN1 -> merged (bf16) ----------------
__global__ __launch_bounds__(256) void k_fix_ln1(
    const unsigned short* __restrict__ b_local, const float* __restrict__ a_local,
    const float* __restrict__ cumP, const float* __restrict__ carryA,
    const unsigned short* __restrict__ carryB,
    const float* __restrict__ g1, const float* __restrict__ bb1,
    unsigned short* __restrict__ merged)
{
    const int row = blockIdx.x;
    const int batch = row >> 12;
    const int t = row & (SEQ-1);
    const int c = t >> 3;
    const int tid = threadIdx.x;

    const float cpv = cumP[row];
    const float a = a_local[row] + cpv * carryA[batch*NCH + c];
    const float inv_a = 1.0f / (a + 1e-8f);

    f32x4 bl = unpack4(reinterpret_cast<const shortx4*>(b_local)[row*256 + tid]);
    f32x4 cb = unpack4(reinterpret_cast<const shortx4*>(carryB)[(batch*NCH + c)*256 + tid]);
    f32x4 o = (bl + cpv*cb) * inv_a;

    float s  = o.x+o.y+o.z+o.w;
    float s2 = o.x*o.x + o.y*o.y + o.z*o.z + o.w*o.w;
    __shared__ float red[8];
    block_reduce2(s, s2, red, tid);

    const float mean = s * (1.0f/DIM);
    const float rstd = rsqrtf(s2*(1.0f/DIM) - mean*mean + 1e-5f);
    f32x4 gg = reinterpret_cast<const f32x4*>(g1)[tid];
    f32x4 bb = reinterpret_cast<const f32x4*>(bb1)[tid];
    f32x4 m = (o - mean)*rstd*gg + bb;
    reinterpret_cast<shortx4*>(merged)[row*256 + tid] = pack4(m);
}

// ---------------- K5: 256x256 deep-pipelined bf16 GEMM ----------------
// BM=BN=256, BK=32, 8 waves (2m x 4n), per-wave C: 128x64 (acc[8][4]).
// LDS ring-4: slot = 32KB (A 16KB + B 16KB), depth-3 tile prefetch,
// counted vmcnt(8) once per K-tile. Subtiles 16x32 bf16 (1024B) with
// col-group XOR swizzle (cg ^= 2 when row&8) on both stage-src and ds_read.
typedef __attribute__((address_space(3))) unsigned int lds_uint;
typedef __attribute__((address_space(1))) unsigned int glob_uint;
static __device__ __forceinline__ void gload16(const unsigned short* g, char* l){
    __builtin_amdgcn_global_load_lds((const glob_uint*)g, (lds_uint*)l, 16, 0, 0);
}
#define SBAR() do { __builtin_amdgcn_sched_barrier(0); __builtin_amdgcn_s_barrier(); __builtin_amdgcn_sched_barrier(0); } while(0)
#define LDSE 136   // padded epilogue row stride (shorts)

__global__ __launch_bounds__(512, 2) void k_gemm(
    const unsigned short* __restrict__ A,    // merged bf16 [16384][1024]
    const unsigned short* __restrict__ Bt,   // Wcat  bf16 [2048][1024]
    const float* __restrict__ rbias, const float* __restrict__ vbias,
    unsigned short* __restrict__ gv)         // bf16 [16384][1024]
{
    __shared__ __align__(16) char lds[131072];
    const int tid  = threadIdx.x;
    const int lane = tid & 63;
    const int wid  = tid >> 6;       // 0..7
    const int wm   = wid >> 2;       // 0..1
    const int wn   = wid & 3;        // 0..3

    // bijective XCD swizzle (nwg=512, %8==0), nt-inner for A-panel L2 reuse
    const int bid  = blockIdx.x;
    const int wgid = (bid & 7)*64 + (bid >> 3);
    const int mt = wgid >> 3, nt = wgid & 7;
    const int m0 = mt*256, n0 = nt*256;

    // staging source (pre-swizzled col-group)
    const int sr  = lane >> 2;
    const int scg = (lane & 3) ^ ((lane >> 5) << 1);
    const unsigned short* gA = A  + (size_t)(m0 + wid*32 + sr)*DIM + scg*8;
    const unsigned short* gB = Bt + (size_t)(n0 + wid*32 + sr)*DIM + scg*8;

    // fragment read offset (matching swizzle)
    const int fr = lane & 15, fq = lane >> 4;
    const int soff = fr*64 + ((fq*16) ^ ((fr & 8) ? 32 : 0));

    f32x4 acc[8][4];
    #pragma unroll
    for (int i = 0; i < 8; ++i)
        #pragma unroll
        for (int j = 0; j < 4; ++j) acc[i][j] = (f32x4){0,0,0,0};

    auto STAGE_A = [&](int tk){   // wave stages subtiles 2*wid, 2*wid+1
        char* dst = &lds[(tk & 3)*32768 + wid*2048];
        const unsigned short* s0 = gA + tk*32;
        gload16(s0,          dst);
        gload16(s0 + 16*DIM, dst + 1024);
    };
    auto STAGE_B = [&](int tk){
        char* dst = &lds[(tk & 3)*32768 + 16384 + wid*2048];
        const unsigned short* s0 = gB + tk*32;
        gload16(s0,          dst);
        gload16(s0 + 16*DIM, dst + 1024);
    };

    // prologue: tiles 0,1,2 in flight; wait tile 0 (8 newer may fly)
    STAGE_A(0); STAGE_B(0);
    STAGE_A(1); STAGE_B(1);
    STAGE_A(2); STAGE_B(2);
    asm volatile("s_waitcnt vmcnt(8)" ::: "memory");
    SBAR();

    for (int t = 0; t < NKT; ++t){
        const char* bufA = &lds[(t & 3)*32768];
        const char* bufB = bufA + 16384;
        shortx8 af[4], bf[4];

        // ---- phase A: A mf0-3 (8 rds) + B nf0-3 (4 rds), stage A(t+3) ----
        #pragma unroll
        for (int mf = 0; mf < 4; ++mf)
            af[mf] = *reinterpret_cast<const shortx8*>(bufA + (wm*8 + mf)*1024 + soff);
        #pragma unroll
        for (int nf = 0; nf < 4; ++nf)
            bf[nf] = *reinterpret_cast<const shortx8*>(bufB + (wn*4 + nf)*1024 + soff);
        if (t + 3 < NKT) STAGE_A(t + 3);
        SBAR();
        asm volatile("s_waitcnt lgkmcnt(0)" ::: "memory");
        __builtin_amdgcn_sched_barrier(0);
        __builtin_amdgcn_s_setprio(1);
        #pragma unroll
        for (int mf = 0; mf < 4; ++mf)
            #pragma unroll
            for (int nf = 0; nf < 4; ++nf)
                acc[mf][nf] = __builtin_amdgcn_mfma_f32_16x16x32_bf16(af[mf], bf[nf], acc[mf][nf], 0, 0, 0);
        __builtin_amdgcn_s_setprio(0);
        SBAR();

        // ---- phase B: A mf4-7 (4 rds, reuse B), stage B(t+3), counted vmcnt --
        #pragma unroll
        for (int mf = 0; mf < 4; ++mf)
            af[mf] = *reinterpret_cast<const shortx8*>(bufA + (wm*8 + mf + 4)*1024 + soff);
        if (t + 3 < NKT) STAGE_B(t + 3);
        if (t <= NKT - 4)      asm volatile("s_waitcnt vmcnt(8)" ::: "memory");
        else if (t == NKT - 3) asm volatile("s_waitcnt vmcnt(4)" ::: "memory");
        else                   asm volatile("s_waitcnt vmcnt(0)" ::: "memory");
        SBAR();
        asm volatile("s_waitcnt lgkmcnt(0)" ::: "memory");
        __builtin_amdgcn_sched_barrier(0);
        __builtin_amdgcn_s_setprio(1);
        #pragma unroll
        for (int mf = 0; mf < 4; ++mf)
            #pragma unroll
            for (int nf = 0; nf < 4; ++nf)
                acc[mf+4][nf] = __builtin_amdgcn_mfma_f32_16x16x32_bf16(af[mf], bf[nf], acc[mf+4][nf], 0, 0, 0);
        __builtin_amdgcn_s_setprio(0);
        SBAR();
    }

    // ---- epilogue: sigmoid(gate)*value -> padded LDS transpose -> store ----
    __syncthreads();
    unsigned short* ep = reinterpret_cast<unsigned short*>(lds);  // [256][LDSE]
    #pragma unroll
    for (int pr = 0; pr < 2; ++pr){
        const int el = wn*32 + pr*16 + fr;         // 0..127 within block
        const float rbe = rbias[nt*128 + el];
        const float vbe = vbias[nt*128 + el];
        #pragma unroll
        for (int mf = 0; mf < 8; ++mf){
            const int rbase = wm*128 + mf*16 + fq*4;
            f32x4 ga = acc[mf][2*pr], va = acc[mf][2*pr+1];
            #pragma unroll
            for (int q = 0; q < 4; ++q){
                const float g = sigmoidf_fast(ga[q] + rbe);
                ep[(rbase + q)*LDSE + el] = f2bf(g*(va[q] + vbe));
            }
        }
    }
    __syncthreads();
    #pragma unroll
    for (int p = 0; p < 8; ++p){
        const int r  = p*32 + (tid >> 4);
        const int c8 = tid & 15;
        shortx8 val = *reinterpret_cast<const shortx8*>(&ep[r*LDSE + c8*8]);
        *reinterpret_cast<shortx8*>(&gv[(size_t)(m0 + r)*DIM + nt*128 + c8*8]) = val;
    }
}

// ---------------- K6: LN2 + residual ----------------
__global__ __launch_bounds__(256) void k_ln2_res(
    const unsigned short* __restrict__ gvb, const unsigned short* __restrict__ shifted,
    const float* __restrict__ g2, const float* __restrict__ b2,
    float* __restrict__ out)
{
    const int row = blockIdx.x, tid = threadIdx.x;
    const int idx = row*256 + tid;
    f32x4 v = unpack4(reinterpret_cast<const shortx4*>(gvb)[idx]);
    float s  = v.x+v.y+v.z+v.w;
    float s2 = v.x*v.x + v.y*v.y + v.z*v.z + v.w*v.w;
    __shared__ float red[8];
    block_reduce2(s, s2, red, tid);
    const float mean = s * (1.0f/DIM);
    const float rstd = rsqrtf(s2*(1.0f/DIM) - mean*mean + 1e-5f);
    f32x4 gg = reinterpret_cast<const f32x4*>(g2)[tid];
    f32x4 bb = reinterpret_cast<const f32x4*>(b2)[tid];
    f32x4 nv = (v - mean)*rstd*gg + bb;
    f32x4 sh = unpack4(reinterpret_cast<const shortx4*>(shifted)[idx]);
    reinterpret_cast<f32x4*>(out)[idx] = sh + nv;
}

extern "C" void kernel_launch(void* const* d_in, const int* in_sizes, int n_in,
                              void* d_out, int out_size, void* d_ws, size_t ws_size,
                              hipStream_t stream)
{
    (void)in_sizes; (void)n_in; (void)out_size; (void)ws_size;
    const float* x     = (const float*)d_in[0];
    const float* xprev = (const float*)d_in[1];
    const float* mu    = (const float*)d_in[2];
    const float* dw    = (const float*)d_in[3];
    const float* db    = (const float*)d_in[4];
    const float* ln1g  = (const float*)d_in[5];
    const float* ln1b  = (const float*)d_in[6];
    const float* Wr    = (const float*)d_in[7];
    const float* Wrb   = (const float*)d_in[8];
    const float* Wv    = (const float*)d_in[9];
    const float* Wvb   = (const float*)d_in[10];
    const float* ln2g  = (const float*)d_in[11];
    const float* ln2b  = (const float*)d_in[12];
    float* out = (float*)d_out;

    char* ws = (char*)d_ws;
    size_t off = 0;
    auto alloc = [&](size_t bytes) -> void* {
        void* p = ws + off;
        off += (bytes + 255) & ~(size_t)255;
        return p;
    };
    unsigned short* shifted = (unsigned short*)alloc((size_t)NROWS*DIM*2);
    unsigned short* b_local = (unsigned short*)alloc((size_t)NROWS*DIM*2);
    unsigned short* merged  = (unsigned short*)alloc((size_t)NROWS*DIM*2);
    unsigned short* carryB  = (unsigned short*)alloc((size_t)BATCH*NCH*DIM*2);
    unsigned short* Wcat    = (unsigned short*)alloc((size_t)2048*1024*2);
    float* a_local          = (float*)alloc((size_t)NROWS*4);
    float* cumP             = (float*)alloc((size_t)NROWS*4);
    float* carryA           = (float*)alloc((size_t)BATCH*NCH*4);
    unsigned short* gvbuf   = b_local;   // b_local dead after k_fix_ln1

    hipLaunchKernelGGL(k_pack_w,    dim3(2048),  dim3(256), 0, stream, Wr, Wv, Wcat);
    hipLaunchKernelGGL(k_shift_scan,dim3(512),   dim3(256), 0, stream,
                       x, xprev, mu, dw, db, shifted, b_local, a_local, cumP);
    hipLaunchKernelGGL(k_combine,   dim3(16),    dim3(256), 0, stream,
                       b_local, a_local, cumP, carryA, carryB);
    hipLaunchKernelGGL(k_fix_ln1,   dim3(16384), dim3(256), 0, stream,
                       b_local, a_local, cumP, carryA, carryB, ln1g, ln1b, merged);
    hipLaunchKernelGGL(k_gemm,      dim3(512),   dim3(512), 0, stream,
                       merged, Wcat, Wrb, Wvb, gvbuf);
    hipLaunchKernelGGL(k_ln2_res,   dim3(16384), dim3(256), 0, stream,
                       gvbuf, shifted, ln2g, ln2b, out);
}

// Round 4
// 215.828 us; speedup vs baseline: 1.0983x; 1.0693x over previous
//
#include <hip/hip_runtime.h>

#define BATCH 4
#define SEQ   4096
#define DIM   1024
#define NCH   512
#define CHK   8
#define NROWS (BATCH*SEQ)
#define NKT   32            // gemm K-tiles (1024/32)

typedef __attribute__((ext_vector_type(4))) float f32x4;
typedef __attribute__((ext_vector_type(8))) short shortx8;
typedef __attribute__((ext_vector_type(4))) short shortx4;

static __device__ __forceinline__ unsigned short f2bf(float f){
    unsigned int u = __float_as_uint(f);
    u += 0x7FFFu + ((u >> 16) & 1u);
    return (unsigned short)(u >> 16);
}
static __device__ __forceinline__ float bf2f(unsigned short h){
    return __uint_as_float(((unsigned int)h) << 16);
}
static __device__ __forceinline__ float sigmoidf_fast(float x){
    return 1.0f / (1.0f + __expf(-x));
}
static __device__ __forceinline__ shortx4 pack4(f32x4 s){
    shortx4 o;
    o.x = (short)f2bf(s.x); o.y = (short)f2bf(s.y);
    o.z = (short)f2bf(s.z); o.w = (short)f2bf(s.w);
    return o;
}
static __device__ __forceinline__ f32x4 unpack4(shortx4 s){
    f32x4 o;
    o.x = bf2f((unsigned short)s.x); o.y = bf2f((unsigned short)s.y);
    o.z = bf2f((unsigned short)s.z); o.w = bf2f((unsigned short)s.w);
    return o;
}

// ---------------- K1: shift + decay + exp + chunk-local scan  (+ fused W-pack) ----
// blocks 0..511: scan (one wave per 8-row chunk). blocks 512..575: pack Wr/Wv -> Wcat.
__global__ __launch_bounds__(256) void k_shift_scan(
    const float* __restrict__ X, const float* __restrict__ XP,
    const float* __restrict__ mu_p, const float* __restrict__ dw,
    const float* __restrict__ db_p,
    const float* __restrict__ Wr, const float* __restrict__ Wv,
    unsigned short* __restrict__ Wcat,
    unsigned short* __restrict__ shifted,
    unsigned short* __restrict__ b_local, float* __restrict__ a_local,
    float* __restrict__ cumP)
{
    const int tid  = threadIdx.x;

    if (blockIdx.x >= 512){            // ---- weight pack path ----
        const int pb = blockIdx.x - 512;       // 0..63
        #pragma unroll 4
        for (int i = 0; i < 32; ++i){
            const int n = pb*32 + i;
            const int grp = n >> 5, r = n & 31;
            const float* src = (r < 16) ? (Wr + (size_t)(grp*16 + r)*DIM)
                                        : (Wv + (size_t)(grp*16 + (r-16))*DIM);
            f32x4 v = reinterpret_cast<const f32x4*>(src)[tid];
            reinterpret_cast<shortx4*>(Wcat)[n*256 + tid] = pack4(v);
        }
        return;
    }

    const int lane = tid & 63;
    const int wid  = tid >> 6;
    const int cid  = blockIdx.x*4 + wid;
    const int batch = cid >> 9;
    const int chunk = cid & (NCH-1);
    const int row0  = batch*SEQ + chunk*CHK;

    const float mu = mu_p[0];
    const float om = 1.0f - mu;
    const float db = db_p[0];

    const f32x4* dwv = reinterpret_cast<const f32x4*>(dw);
    const f32x4 w0 = dwv[lane], w1 = dwv[64+lane], w2 = dwv[128+lane], w3 = dwv[192+lane];

    f32x4 b0 = {0,0,0,0}, b1 = {0,0,0,0}, b2 = {0,0,0,0}, b3 = {0,0,0,0};
    float a_run = 0.f, cp = 1.f;

    const f32x4* Xv  = reinterpret_cast<const f32x4*>(X);
    const f32x4* XPv = reinterpret_cast<const f32x4*>(XP);
    shortx4* BL = reinterpret_cast<shortx4*>(b_local);
    shortx4* SH = reinterpret_cast<shortx4*>(shifted);

    for (int r = 0; r < CHK; ++r){
        const int row = row0 + r;
        const int rb  = row*(DIM/4);

        f32x4 x0 = Xv[rb+lane],     x1 = Xv[rb+64+lane],
              x2 = Xv[rb+128+lane], x3 = Xv[rb+192+lane];
        f32x4 p0 = XPv[rb+lane],     p1 = XPv[rb+64+lane],
              p2 = XPv[rb+128+lane], p3 = XPv[rb+192+lane];
        f32x4 s0 = mu*x0 + om*p0, s1 = mu*x1 + om*p1;
        f32x4 s2 = mu*x2 + om*p2, s3 = mu*x3 + om*p3;

        SH[rb+lane]     = pack4(s0);
        SH[rb+64+lane]  = pack4(s1);
        SH[rb+128+lane] = pack4(s2);
        SH[rb+192+lane] = pack4(s3);

        float dot = s0.x*w0.x + s0.y*w0.y + s0.z*w0.z + s0.w*w0.w
                  + s1.x*w1.x + s1.y*w1.y + s1.z*w1.z + s1.w*w1.w
                  + s2.x*w2.x + s2.y*w2.y + s2.z*w2.z + s2.w*w2.w
                  + s3.x*w3.x + s3.y*w3.y + s3.z*w3.z + s3.w*w3.w;

        f32x4 e0, e1, e2, e3;
        e0.x=__expf(s0.x); e0.y=__expf(s0.y); e0.z=__expf(s0.z); e0.w=__expf(s0.w);
        e1.x=__expf(s1.x); e1.y=__expf(s1.y); e1.z=__expf(s1.z); e1.w=__expf(s1.w);
        e2.x=__expf(s2.x); e2.y=__expf(s2.y); e2.z=__expf(s2.z); e2.w=__expf(s2.w);
        e3.x=__expf(s3.x); e3.y=__expf(s3.y); e3.z=__expf(s3.z); e3.w=__expf(s3.w);
        float ea = e0.x+e0.y+e0.z+e0.w + e1.x+e1.y+e1.z+e1.w
                 + e2.x+e2.y+e2.z+e2.w + e3.x+e3.y+e3.z+e3.w;

        #pragma unroll
        for (int off = 1; off < 64; off <<= 1){
            dot += __shfl_xor(dot, off, 64);
            ea  += __shfl_xor(ea,  off, 64);
        }

        const float dt = sigmoidf_fast(dot + db);
        a_run = dt*a_run + ea;
        cp   *= dt;
        b0 = dt*b0 + e0*s0;  b1 = dt*b1 + e1*s1;
        b2 = dt*b2 + e2*s2;  b3 = dt*b3 + e3*s3;

        BL[rb+lane]     = pack4(b0);
        BL[rb+64+lane]  = pack4(b1);
        BL[rb+128+lane] = pack4(b2);
        BL[rb+192+lane] = pack4(b3);
        if (lane == 0){ a_local[row] = a_run; cumP[row] = cp; }
    }
}

// ---------------- K2: sequential carry combine (depth-16 vector prefetch) ----
// 16 blocks x 64 threads; thread owns 4 consecutive d.
__global__ __launch_bounds__(64) void k_combine(
    const unsigned short* __restrict__ b_local, const float* __restrict__ a_local,
    const float* __restrict__ cumP,
    float* __restrict__ carryA, unsigned short* __restrict__ carryB)
{
    const int batch = blockIdx.x >> 2;
    const int dseg  = blockIdx.x & 3;
    const int tid = threadIdx.x;
    const int d0 = dseg*256 + tid*4;

    __shared__ float sP[NCH], sA[NCH];
    for (int c = tid; c < NCH; c += 64){
        const int er = batch*SEQ + c*CHK + (CHK-1);
        sP[c] = cumP[er];
        sA[c] = a_local[er];
    }
    __syncthreads();

    const unsigned short* bl = b_local + (size_t)batch*SEQ*DIM + d0;
    unsigned short* cB = carryB + (size_t)batch*NCH*DIM + d0;
    const bool wA = (dseg == 0 && tid == 0);
    float* cAp = carryA + batch*NCH;

    shortx4 pf[16];
    #pragma unroll
    for (int i = 0; i < 16; ++i)
        pf[i] = *reinterpret_cast<const shortx4*>(bl + (i*CHK + CHK-1)*DIM);

    f32x4 cb = {0,0,0,0};
    float ca = 0.f;

    for (int cc = 0; cc < NCH; cc += 16){
        const bool more = (cc + 16 < NCH);
        #pragma unroll
        for (int k = 0; k < 16; ++k){
            const int c = cc + k;
            f32x4 v = unpack4(pf[k]);                       // static index
            if (more)
                pf[k] = *reinterpret_cast<const shortx4*>(bl + ((c+16)*CHK + CHK-1)*DIM);
            *reinterpret_cast<shortx4*>(cB + (size_t)c*DIM) = pack4(cb);
            if (wA) cAp[c] = ca;
            const float p = sP[c];
            cb = p*cb + v;
            ca = p*ca + sA[c];
        }
    }
}

static __device__ __forceinline__ void block_reduce2(float& s, float& s2, float* red, int tid){
    #pragma unroll
    for (int off = 1; off < 64; off <<= 1){
        s  += __shfl_xor(s,  off, 64);
        s2 += __shfl_xor(s2, off, 64);
    }
    const int wid = tid >> 6, lane = tid & 63;
    if (lane == 0){ red[wid] = s; red[4+wid] = s2; }
    __syncthreads();
    s  = red[0]+red[1]+red[2]+red[3];
    s2 = red[4]+red[5]+red[6]+red[7];
}

// ---------------- K3: carry fixup + divide + LN1 -> merged (bf16) ----------------
__global__ __launch_bounds__(256) void k_fix_ln1(
    const unsigned short* __restrict__ b_local, const float* __restrict__ a_local,
    const float* __restrict__ cumP, const float* __restrict__ carryA,
    const unsigned short* __restrict__ carryB,
    const float* __restrict__ g1, const float* __restrict__ bb1,
    unsigned short* __restrict__ merged)
{
    const int row = blockIdx.x;
    const int batch = row >> 12;
    const int t = row & (SEQ-1);
    const int c = t >> 3;
    const int tid = threadIdx.x;

    const float cpv = cumP[row];
    const float a = a_local[row] + cpv * carryA[batch*NCH + c];
    const float inv_a = 1.0f / (a + 1e-8f);

    f32x4 bl = unpack4(reinterpret_cast<const shortx4*>(b_local)[row*256 + tid]);
    f32x4 cb = unpack4(reinterpret_cast<const shortx4*>(carryB)[(batch*NCH + c)*256 + tid]);
    f32x4 o = (bl + cpv*cb) * inv_a;

    float s  = o.x+o.y+o.z+o.w;
    float s2 = o.x*o.x + o.y*o.y + o.z*o.z + o.w*o.w;
    __shared__ float red[8];
    block_reduce2(s, s2, red, tid);

    const float mean = s * (1.0f/DIM);
    const float rstd = rsqrtf(s2*(1.0f/DIM) - mean*mean + 1e-5f);
    f32x4 gg = reinterpret_cast<const f32x4*>(g1)[tid];
    f32x4 bb = reinterpret_cast<const f32x4*>(bb1)[tid];
    f32x4 m = (o - mean)*rstd*gg + bb;
    reinterpret_cast<shortx4*>(merged)[row*256 + tid] = pack4(m);
}

// ---------------- K5: 256x256 bf16 GEMM, free-flowing waves ----------------
// BM=BN=256, BK=32, 8 waves (2m x 4n), per-wave C: 128x64 (acc[8][4]).
// LDS ring-4 (32KB slots), depth-3 prefetch, counted vmcnt(8)/tile,
// ONE barrier per K-tile; intra-tile sync = per-wave derived lgkmcnt waits.
// Subtiles 16x32 bf16 (1024B), col-group XOR swizzle (cg^=2 when row&8)
// applied identically on stage-source and ds_read.
typedef __attribute__((address_space(3))) unsigned int lds_uint;
typedef __attribute__((address_space(1))) unsigned int glob_uint;
static __device__ __forceinline__ void gload16(const unsigned short* g, char* l){
    __builtin_amdgcn_global_load_lds((const glob_uint*)g, (lds_uint*)l, 16, 0, 0);
}
#define SBAR() do { __builtin_amdgcn_sched_barrier(0); __builtin_amdgcn_s_barrier(); __builtin_amdgcn_sched_barrier(0); } while(0)
#define LDSE 136   // padded epilogue row stride (shorts)

__global__ __launch_bounds__(512, 2) void k_gemm(
    const unsigned short* __restrict__ A,    // merged bf16 [16384][1024]
    const unsigned short* __restrict__ Bt,   // Wcat  bf16 [2048][1024]
    const float* __restrict__ rbias, const float* __restrict__ vbias,
    unsigned short* __restrict__ gv)         // bf16 [16384][1024]
{
    __shared__ __align__(16) char lds[131072];
    const int tid  = threadIdx.x;
    const int lane = tid & 63;
    const int wid  = tid >> 6;       // 0..7
    const int wm   = wid >> 2;       // 0..1
    const int wn   = wid & 3;        // 0..3

    // bijective XCD swizzle (nwg=512, %8==0), nt-inner for A-panel L2 reuse
    const int bid  = blockIdx.x;
    const int wgid = (bid & 7)*64 + (bid >> 3);
    const int mt = wgid >> 3, nt = wgid & 7;
    const int m0 = mt*256, n0 = nt*256;

    // staging source (pre-swizzled col-group)
    const int sr  = lane >> 2;
    const int scg = (lane & 3) ^ ((lane >> 5) << 1);
    const unsigned short* gA = A  + (size_t)(m0 + wid*32 + sr)*DIM + scg*8;
    const unsigned short* gB = Bt + (size_t)(n0 + wid*32 + sr)*DIM + scg*8;

    // fragment read offset (matching swizzle)
    const int fr = lane & 15, fq = lane >> 4;
    const int soff = fr*64 + ((fq*16) ^ ((fr & 8) ? 32 : 0));

    f32x4 acc[8][4];
    #pragma unroll
    for (int i = 0; i < 8; ++i)
        #pragma unroll
        for (int j = 0; j < 4; ++j) acc[i][j] = (f32x4){0,0,0,0};

    auto STAGE_A = [&](int tk){
        char* dst = &lds[(tk & 3)*32768 + wid*2048];
        const unsigned short* s0 = gA + tk*32;
        gload16(s0,          dst);
        gload16(s0 + 16*DIM, dst + 1024);
    };
    auto STAGE_B = [&](int tk){
        char* dst = &lds[(tk & 3)*32768 + 16384 + wid*2048];
        const unsigned short* s0 = gB + tk*32;
        gload16(s0,          dst);
        gload16(s0 + 16*DIM, dst + 1024);
    };

    // prologue: tiles 0,1,2 in flight; tile 0 landed when <=8 outstanding
    STAGE_A(0); STAGE_B(0);
    STAGE_A(1); STAGE_B(1);
    STAGE_A(2); STAGE_B(2);
    asm volatile("s_waitcnt vmcnt(8)" ::: "memory");
    SBAR();

    for (int t = 0; t < NKT; ++t){
        const char* bufA = &lds[(t & 3)*32768];
        const char* bufB = bufA + 16384;

        // stage t+3 early (vmcnt-tracked, independent of lgkm)
        if (t + 3 < NKT){ STAGE_A(t + 3); STAGE_B(t + 3); }

        // group 1: af0-3 + bf0-3 (8 ds_reads, issue-order pinned)
        shortx8 af0[4], af1[4], bf[4];
        #pragma unroll
        for (int mf = 0; mf < 4; ++mf)
            af0[mf] = *reinterpret_cast<const shortx8*>(bufA + (wm*8 + mf)*1024 + soff);
        #pragma unroll
        for (int nf = 0; nf < 4; ++nf)
            bf[nf] = *reinterpret_cast<const shortx8*>(bufB + (wn*4 + nf)*1024 + soff);
        __builtin_amdgcn_sched_barrier(0);
        // group 2: af4-7 (4 ds_reads)
        #pragma unroll
        for (int mf = 0; mf < 4; ++mf)
            af1[mf] = *reinterpret_cast<const shortx8*>(bufA + (wm*8 + mf + 4)*1024 + soff);

        asm volatile("s_waitcnt lgkmcnt(4)" ::: "memory");   // group 1 landed
        __builtin_amdgcn_sched_barrier(0);
        __builtin_amdgcn_s_setprio(1);
        #pragma unroll
        for (int mf = 0; mf < 4; ++mf)
            #pragma unroll
            for (int nf = 0; nf < 4; ++nf)
                acc[mf][nf] = __builtin_amdgcn_mfma_f32_16x16x32_bf16(af0[mf], bf[nf], acc[mf][nf], 0, 0, 0);
        __builtin_amdgcn_s_setprio(0);

        asm volatile("s_waitcnt lgkmcnt(0)" ::: "memory");   // group 2 landed
        __builtin_amdgcn_sched_barrier(0);
        __builtin_amdgcn_s_setprio(1);
        #pragma unroll
        for (int mf = 0; mf < 4; ++mf)
            #pragma unroll
            for (int nf = 0; nf < 4; ++nf)
                acc[mf+4][nf] = __builtin_amdgcn_mfma_f32_16x16x32_bf16(af1[mf], bf[nf], acc[mf+4][nf], 0, 0, 0);
        __builtin_amdgcn_s_setprio(0);

        // counted vmcnt: guarantee tile t+1 fully in LDS before next iter
        if (t <= NKT - 4)      asm volatile("s_waitcnt vmcnt(8)" ::: "memory");
        else if (t == NKT - 3) asm volatile("s_waitcnt vmcnt(4)" ::: "memory");
        else                   asm volatile("s_waitcnt vmcnt(0)" ::: "memory");
        SBAR();   // single barrier per K-tile (ring-4 reuse safety)
    }

    // ---- epilogue: sigmoid(gate)*value -> padded LDS transpose -> store ----
    __syncthreads();
    unsigned short* ep = reinterpret_cast<unsigned short*>(lds);  // [256][LDSE]
    #pragma unroll
    for (int pr = 0; pr < 2; ++pr){
        const int el = wn*32 + pr*16 + fr;
        const float rbe = rbias[nt*128 + el];
        const float vbe = vbias[nt*128 + el];
        #pragma unroll
        for (int mf = 0; mf < 8; ++mf){
            const int rbase = wm*128 + mf*16 + fq*4;
            f32x4 ga = acc[mf][2*pr], va = acc[mf][2*pr+1];
            #pragma unroll
            for (int q = 0; q < 4; ++q){
                const float g = sigmoidf_fast(ga[q] + rbe);
                ep[(rbase + q)*LDSE + el] = f2bf(g*(va[q] + vbe));
            }
        }
    }
    __syncthreads();
    #pragma unroll
    for (int p = 0; p < 8; ++p){
        const int r  = p*32 + (tid >> 4);
        const int c8 = tid & 15;
        shortx8 val = *reinterpret_cast<const shortx8*>(&ep[r*LDSE + c8*8]);
        *reinterpret_cast<shortx8*>(&gv[(size_t)(m0 + r)*DIM + nt*128 + c8*8]) = val;
    }
}

// ---------------- K6: LN2 + residual ----------------
__global__ __launch_bounds__(256) void k_ln2_res(
    const unsigned short* __restrict__ gvb, const unsigned short* __restrict__ shifted,
    const float* __restrict__ g2, const float* __restrict__ b2,
    float* __restrict__ out)
{
    const int row = blockIdx.x, tid = threadIdx.x;
    const int idx = row*256 + tid;
    f32x4 v = unpack4(reinterpret_cast<const shortx4*>(gvb)[idx]);
    float s  = v.x+v.y+v.z+v.w;
    float s2 = v.x*v.x + v.y*v.y + v.z*v.z + v.w*v.w;
    __shared__ float red[8];
    block_reduce2(s, s2, red, tid);
    const float mean = s * (1.0f/DIM);
    const float rstd = rsqrtf(s2*(1.0f/DIM) - mean*mean + 1e-5f);
    f32x4 gg = reinterpret_cast<const f32x4*>(g2)[tid];
    f32x4 bb = reinterpret_cast<const f32x4*>(b2)[tid];
    f32x4 nv = (v - mean)*rstd*gg + bb;
    f32x4 sh = unpack4(reinterpret_cast<const shortx4*>(shifted)[idx]);
    reinterpret_cast<f32x4*>(out)[idx] = sh + nv;
}

extern "C" void kernel_launch(void* const* d_in, const int* in_sizes, int n_in,
                              void* d_out, int out_size, void* d_ws, size_t ws_size,
                              hipStream_t stream)
{
    (void)in_sizes; (void)n_in; (void)out_size; (void)ws_size;
    const float* x     = (const float*)d_in[0];
    const float* xprev = (const float*)d_in[1];
    const float* mu    = (const float*)d_in[2];
    const float* dw    = (const float*)d_in[3];
    const float* db    = (const float*)d_in[4];
    const float* ln1g  = (const float*)d_in[5];
    const float* ln1b  = (const float*)d_in[6];
    const float* Wr    = (const float*)d_in[7];
    const float* Wrb   = (const float*)d_in[8];
    const float* Wv    = (const float*)d_in[9];
    const float* Wvb   = (const float*)d_in[10];
    const float* ln2g  = (const float*)d_in[11];
    const float* ln2b  = (const float*)d_in[12];
    float* out = (float*)d_out;

    char* ws = (char*)d_ws;
    size_t off = 0;
    auto alloc = [&](size_t bytes) -> void* {
        void* p = ws + off;
        off += (bytes + 255) & ~(size_t)255;
        return p;
    };
    unsigned short* shifted = (unsigned short*)alloc((size_t)NROWS*DIM*2);
    unsigned short* b_local = (unsigned short*)alloc((size_t)NROWS*DIM*2);
    unsigned short* merged  = (unsigned short*)alloc((size_t)NROWS*DIM*2);
    unsigned short* carryB  = (unsigned short*)alloc((size_t)BATCH*NCH*DIM*2);
    unsigned short* Wcat    = (unsigned short*)alloc((size_t)2048*1024*2);
    float* a_local          = (float*)alloc((size_t)NROWS*4);
    float* cumP             = (float*)alloc((size_t)NROWS*4);
    float* carryA           = (float*)alloc((size_t)BATCH*NCH*4);
    unsigned short* gvbuf   = b_local;   // b_local dead after k_fix_ln1

    hipLaunchKernelGGL(k_shift_scan, dim3(576),   dim3(256), 0, stream,
                       x, xprev, mu, dw, db, Wr, Wv, Wcat, shifted, b_local, a_local, cumP);
    hipLaunchKernelGGL(k_combine,    dim3(16),    dim3(64),  0, stream,
                       b_local, a_local, cumP, carryA, carryB);
    hipLaunchKernelGGL(k_fix_ln1,    dim3(16384), dim3(256), 0, stream,
                       b_local, a_local, cumP, carryA, carryB, ln1g, ln1b, merged);
    hipLaunchKernelGGL(k_gemm,       dim3(512),   dim3(512), 0, stream,
                       merged, Wcat, Wrb, Wvb, gvbuf);
    hipLaunchKernelGGL(k_ln2_res,    dim3(16384), dim3(256), 0, stream,
                       gvbuf, shifted, ln2g, ln2b, out);
}

// Round 6
// 206.026 us; speedup vs baseline: 1.1506x; 1.0476x over previous
//
#include <hip/hip_runtime.h>

#define BATCH 4
#define SEQ   4096
#define DIM   1024
#define NCH   512
#define CHK   8
#define NROWS (BATCH*SEQ)
#define NTG   16            // gemm K-tiles (1024/64)

typedef __attribute__((ext_vector_type(4))) float f32x4;
typedef __attribute__((ext_vector_type(8))) short shortx8;
typedef __attribute__((ext_vector_type(4))) short shortx4;

static __device__ __forceinline__ unsigned short f2bf(float f){
    unsigned int u = __float_as_uint(f);
    u += 0x7FFFu + ((u >> 16) & 1u);
    return (unsigned short)(u >> 16);
}
static __device__ __forceinline__ float bf2f(unsigned short h){
    return __uint_as_float(((unsigned int)h) << 16);
}
static __device__ __forceinline__ float sigmoidf_fast(float x){
    return 1.0f / (1.0f + __expf(-x));
}
static __device__ __forceinline__ shortx4 pack4(f32x4 s){
    shortx4 o;
    o.x = (short)f2bf(s.x); o.y = (short)f2bf(s.y);
    o.z = (short)f2bf(s.z); o.w = (short)f2bf(s.w);
    return o;
}
static __device__ __forceinline__ f32x4 unpack4(shortx4 s){
    f32x4 o;
    o.x = bf2f((unsigned short)s.x); o.y = bf2f((unsigned short)s.y);
    o.z = bf2f((unsigned short)s.z); o.w = bf2f((unsigned short)s.w);
    return o;
}

// ---------------- K1: shift + decay + exp + chunk-local scan (+ fused W-pack) ----
__global__ __launch_bounds__(256) void k_shift_scan(
    const float* __restrict__ X, const float* __restrict__ XP,
    const float* __restrict__ mu_p, const float* __restrict__ dw,
    const float* __restrict__ db_p,
    const float* __restrict__ Wr, const float* __restrict__ Wv,
    unsigned short* __restrict__ Wcat,
    unsigned short* __restrict__ shifted,
    unsigned short* __restrict__ b_local, float* __restrict__ a_local,
    float* __restrict__ cumP)
{
    const int tid  = threadIdx.x;

    if (blockIdx.x >= 512){            // ---- weight pack path ----
        const int pb = blockIdx.x - 512;       // 0..63
        #pragma unroll 4
        for (int i = 0; i < 32; ++i){
            const int n = pb*32 + i;
            const int grp = n >> 5, r = n & 31;
            const float* src = (r < 16) ? (Wr + (size_t)(grp*16 + r)*DIM)
                                        : (Wv + (size_t)(grp*16 + (r-16))*DIM);
            f32x4 v = reinterpret_cast<const f32x4*>(src)[tid];
            reinterpret_cast<shortx4*>(Wcat)[n*256 + tid] = pack4(v);
        }
        return;
    }

    const int lane = tid & 63;
    const int wid  = tid >> 6;
    const int cid  = blockIdx.x*4 + wid;
    const int batch = cid >> 9;
    const int chunk = cid & (NCH-1);
    const int row0  = batch*SEQ + chunk*CHK;

    const float mu = mu_p[0];
    const float om = 1.0f - mu;
    const float db = db_p[0];

    const f32x4* dwv = reinterpret_cast<const f32x4*>(dw);
    const f32x4 w0 = dwv[lane], w1 = dwv[64+lane], w2 = dwv[128+lane], w3 = dwv[192+lane];

    f32x4 b0 = {0,0,0,0}, b1 = {0,0,0,0}, b2 = {0,0,0,0}, b3 = {0,0,0,0};
    float a_run = 0.f, cp = 1.f;

    const f32x4* Xv  = reinterpret_cast<const f32x4*>(X);
    const f32x4* XPv = reinterpret_cast<const f32x4*>(XP);
    shortx4* BL = reinterpret_cast<shortx4*>(b_local);
    shortx4* SH = reinterpret_cast<shortx4*>(shifted);

    for (int r = 0; r < CHK; ++r){
        const int row = row0 + r;
        const int rb  = row*(DIM/4);

        f32x4 x0 = Xv[rb+lane],     x1 = Xv[rb+64+lane],
              x2 = Xv[rb+128+lane], x3 = Xv[rb+192+lane];
        f32x4 p0 = XPv[rb+lane],     p1 = XPv[rb+64+lane],
              p2 = XPv[rb+128+lane], p3 = XPv[rb+192+lane];
        f32x4 s0 = mu*x0 + om*p0, s1 = mu*x1 + om*p1;
        f32x4 s2 = mu*x2 + om*p2, s3 = mu*x3 + om*p3;

        SH[rb+lane]     = pack4(s0);
        SH[rb+64+lane]  = pack4(s1);
        SH[rb+128+lane] = pack4(s2);
        SH[rb+192+lane] = pack4(s3);

        float dot = s0.x*w0.x + s0.y*w0.y + s0.z*w0.z + s0.w*w0.w
                  + s1.x*w1.x + s1.y*w1.y + s1.z*w1.z + s1.w*w1.w
                  + s2.x*w2.x + s2.y*w2.y + s2.z*w2.z + s2.w*w2.w
                  + s3.x*w3.x + s3.y*w3.y + s3.z*w3.z + s3.w*w3.w;

        f32x4 e0, e1, e2, e3;
        e0.x=__expf(s0.x); e0.y=__expf(s0.y); e0.z=__expf(s0.z); e0.w=__expf(s0.w);
        e1.x=__expf(s1.x); e1.y=__expf(s1.y); e1.z=__expf(s1.z); e1.w=__expf(s1.w);
        e2.x=__expf(s2.x); e2.y=__expf(s2.y); e2.z=__expf(s2.z); e2.w=__expf(s2.w);
        e3.x=__expf(s3.x); e3.y=__expf(s3.y); e3.z=__expf(s3.z); e3.w=__expf(s3.w);
        float ea = e0.x+e0.y+e0.z+e0.w + e1.x+e1.y+e1.z+e1.w
                 + e2.x+e2.y+e2.z+e2.w + e3.x+e3.y+e3.z+e3.w;

        #pragma unroll
        for (int off = 1; off < 64; off <<= 1){
            dot += __shfl_xor(dot, off, 64);
            ea  += __shfl_xor(ea,  off, 64);
        }

        const float dt = sigmoidf_fast(dot + db);
        a_run = dt*a_run + ea;
        cp   *= dt;
        b0 = dt*b0 + e0*s0;  b1 = dt*b1 + e1*s1;
        b2 = dt*b2 + e2*s2;  b3 = dt*b3 + e3*s3;

        BL[rb+lane]     = pack4(b0);
        BL[rb+64+lane]  = pack4(b1);
        BL[rb+128+lane] = pack4(b2);
        BL[rb+192+lane] = pack4(b3);
        if (lane == 0){ a_local[row] = a_run; cumP[row] = cp; }
    }
}

// ---------------- K2: sequential carry combine (depth-16 vector prefetch) ----
__global__ __launch_bounds__(64) void k_combine(
    const unsigned short* __restrict__ b_local, const float* __restrict__ a_local,
    const float* __restrict__ cumP,
    float* __restrict__ carryA, unsigned short* __restrict__ carryB)
{
    const int batch = blockIdx.x >> 2;
    const int dseg  = blockIdx.x & 3;
    const int tid = threadIdx.x;
    const int d0 = dseg*256 + tid*4;

    __shared__ float sP[NCH], sA[NCH];
    for (int c = tid; c < NCH; c += 64){
        const int er = batch*SEQ + c*CHK + (CHK-1);
        sP[c] = cumP[er];
        sA[c] = a_local[er];
    }
    __syncthreads();

    const unsigned short* bl = b_local + (size_t)batch*SEQ*DIM + d0;
    unsigned short* cB = carryB + (size_t)batch*NCH*DIM + d0;
    const bool wA = (dseg == 0 && tid == 0);
    float* cAp = carryA + batch*NCH;

    shortx4 pf[16];
    #pragma unroll
    for (int i = 0; i < 16; ++i)
        pf[i] = *reinterpret_cast<const shortx4*>(bl + (i*CHK + CHK-1)*DIM);

    f32x4 cb = {0,0,0,0};
    float ca = 0.f;

    for (int cc = 0; cc < NCH; cc += 16){
        const bool more = (cc + 16 < NCH);
        #pragma unroll
        for (int k = 0; k < 16; ++k){
            const int c = cc + k;
            f32x4 v = unpack4(pf[k]);
            if (more)
                pf[k] = *reinterpret_cast<const shortx4*>(bl + ((c+16)*CHK + CHK-1)*DIM);
            *reinterpret_cast<shortx4*>(cB + (size_t)c*DIM) = pack4(cb);
            if (wA) cAp[c] = ca;
            const float p = sP[c];
            cb = p*cb + v;
            ca = p*ca + sA[c];
        }
    }
}

// ---------------- K3: carry fixup + divide + LN1 -> merged (wave-per-row) ----
__global__ __launch_bounds__(256) void k_fix_ln1(
    const unsigned short* __restrict__ b_local, const float* __restrict__ a_local,
    const float* __restrict__ cumP, const float* __restrict__ carryA,
    const unsigned short* __restrict__ carryB,
    const float* __restrict__ g1, const float* __restrict__ bb1,
    unsigned short* __restrict__ merged)
{
    const int tid = threadIdx.x, lane = tid & 63, wid = tid >> 6;
    const int row = blockIdx.x*4 + wid;
    const int batch = row >> 12;
    const int c = (row & (SEQ-1)) >> 3;

    const float cpv = cumP[row];
    const float a = a_local[row] + cpv * carryA[batch*NCH + c];
    const float inv_a = 1.0f / (a + 1e-8f);

    const shortx4* BL = reinterpret_cast<const shortx4*>(b_local) + (size_t)row*256;
    const shortx4* CB = reinterpret_cast<const shortx4*>(carryB) + (size_t)(batch*NCH + c)*256;

    f32x4 o[4];
    float s = 0.f, s2 = 0.f;
    #pragma unroll
    for (int j = 0; j < 4; ++j){
        f32x4 bl = unpack4(BL[j*64 + lane]);
        f32x4 cb = unpack4(CB[j*64 + lane]);
        f32x4 v = (bl + cpv*cb) * inv_a;
        o[j] = v;
        s  += v.x+v.y+v.z+v.w;
        s2 += v.x*v.x + v.y*v.y + v.z*v.z + v.w*v.w;
    }
    #pragma unroll
    for (int off = 1; off < 64; off <<= 1){
        s  += __shfl_xor(s,  off, 64);
        s2 += __shfl_xor(s2, off, 64);
    }
    const float mean = s * (1.0f/DIM);
    const float rstd = rsqrtf(s2*(1.0f/DIM) - mean*mean + 1e-5f);
    shortx4* MG = reinterpret_cast<shortx4*>(merged) + (size_t)row*256;
    #pragma unroll
    for (int j = 0; j < 4; ++j){
        f32x4 gg = reinterpret_cast<const f32x4*>(g1)[j*64 + lane];
        f32x4 bb = reinterpret_cast<const f32x4*>(bb1)[j*64 + lane];
        MG[j*64 + lane] = pack4((o[j] - mean)*rstd*gg + bb);
    }
}

// ---------------- K5: 256x256 bf16 GEMM, quadrant 4-phase (m201 discipline) --
// BK=64; 2 LDS bufs x 64KB; buf = {A0,A1,B0,B1} 16KB pieces (each = 128 rows
// x 64 cols as 16 swizzled 16x32 subtiles). Phases per tile T (C-quadrants):
//   ph0 Q00: read A0(8)+B0(4); stage (T+1).A0; vmcnt(4); 16 MFMA
//   ph1 Q01: read B1(4)      ; stage (T+1).B0; vmcnt(4); 16 MFMA
//   ph2 Q11: read A1(8)      ; stage (T+1).B1; vmcnt(4); 16 MFMA
//   ph3 Q10: (regs held)     ; stage (T+1).A1; vmcnt(4); 16 MFMA
// Stage order == consumption order => uniform vmcnt(4) lands exactly the
// piece needed next phase. (Round-5 bug: lead-7 staging wrote tile T+2 into
// the live buffer.)
typedef __attribute__((address_space(3))) unsigned int lds_uint;
typedef __attribute__((address_space(1))) unsigned int glob_uint;
static __device__ __forceinline__ void gload16(const unsigned short* g, char* l){
    __builtin_amdgcn_global_load_lds((const glob_uint*)g, (lds_uint*)l, 16, 0, 0);
}
#define SBAR() do { __builtin_amdgcn_sched_barrier(0); __builtin_amdgcn_s_barrier(); __builtin_amdgcn_sched_barrier(0); } while(0)
#define LGKM0() do { asm volatile("s_waitcnt lgkmcnt(0)" ::: "memory"); __builtin_amdgcn_sched_barrier(0); } while(0)
#define VMC(n)  asm volatile("s_waitcnt vmcnt(" #n ")" ::: "memory")
#define LDSE 136

__global__ __launch_bounds__(512, 2) void k_gemm(
    const unsigned short* __restrict__ A,    // merged bf16 [16384][1024]
    const unsigned short* __restrict__ Bt,   // Wcat  bf16 [2048][1024]
    const float* __restrict__ rbias, const float* __restrict__ vbias,
    unsigned short* __restrict__ gv)         // bf16 [16384][1024]
{
    __shared__ __align__(16) char lds[131072];
    const int tid  = threadIdx.x;
    const int lane = tid & 63;
    const int wid  = tid >> 6;
    const int wqm  = wid >> 2;       // 0..1: 64-row slice within quadrant
    const int wqn  = wid & 3;        // 0..3: 32-col slice within quadrant

    const int bid  = blockIdx.x;
    const int wgid = (bid & 7)*64 + (bid >> 3);
    const int mt = wgid >> 3, nt = wgid & 7;
    const int m0 = mt*256, n0 = nt*256;

    // staging source (pre-swizzled col-group): lane -> row rin, colgrp scg
    const int rin = lane >> 2;
    const int scg = (lane & 3) ^ (((lane >> 5) & 1) << 1);
    const unsigned short* gA = A  + (size_t)(m0 + wid*16 + rin)*DIM + scg*8;
    const unsigned short* gB = Bt + (size_t)(n0 + wid*16 + rin)*DIM + scg*8;

    // fragment read offset (matching swizzle)
    const int fr = lane & 15, fq = lane >> 4;
    const int soff = fr*64 + ((fq*16) ^ ((fr & 8) ? 32 : 0));

    f32x4 acc0[8], acc1[8], acc2[8], acc3[8];
    #pragma unroll
    for (int i = 0; i < 8; ++i){
        acc0[i] = (f32x4){0,0,0,0}; acc1[i] = (f32x4){0,0,0,0};
        acc2[i] = (f32x4){0,0,0,0}; acc3[i] = (f32x4){0,0,0,0};
    }

    // piece: 0=A0, 1=B0, 2=B1, 3=A1 (issue order == consumption order)
    auto STAGE = [&](int Tk, int piece){
        const int isA = (piece == 0 || piece == 3);
        const int h   = (piece >= 2) ? 1 : 0;
        char* dst = lds + (Tk & 1)*65536 + (isA ? 0 : 32768) + h*16384 + wid*2048;
        const unsigned short* s = (isA ? gA : gB) + (size_t)(h*128)*DIM + Tk*64;
        gload16(s,      dst);            // subtile (rowblk=wid, kb=0)
        gload16(s + 32, dst + 1024);     // subtile (rowblk=wid, kb=1)
    };

    shortx8 aA[8], bB0[4], bB1[4];
    auto LOAD_A = [&](const char* base){
        #pragma unroll
        for (int rf = 0; rf < 4; ++rf)
            #pragma unroll
            for (int kb = 0; kb < 2; ++kb)
                aA[rf*2+kb] = *reinterpret_cast<const shortx8*>(
                    base + (wqm*4 + rf)*2048 + kb*1024 + soff);
    };
    auto LOAD_B = [&](const char* base, shortx8* dst){
        #pragma unroll
        for (int cf = 0; cf < 2; ++cf)
            #pragma unroll
            for (int kb = 0; kb < 2; ++kb)
                dst[cf*2+kb] = *reinterpret_cast<const shortx8*>(
                    base + (wqn*2 + cf)*2048 + kb*1024 + soff);
    };

    #define MFMA16(ACC, BX)                                                     \
        __builtin_amdgcn_s_setprio(1);                                          \
        _Pragma("unroll")                                                       \
        for (int rf = 0; rf < 4; ++rf)                                          \
            _Pragma("unroll")                                                   \
            for (int cf = 0; cf < 2; ++cf){                                     \
                ACC[rf*2+cf] = __builtin_amdgcn_mfma_f32_16x16x32_bf16(         \
                    aA[rf*2+0], BX[cf*2+0], ACC[rf*2+cf], 0,0,0);               \
                ACC[rf*2+cf] = __builtin_amdgcn_mfma_f32_16x16x32_bf16(         \
                    aA[rf*2+1], BX[cf*2+1], ACC[rf*2+cf], 0,0,0);               \
            }                                                                   \
        __builtin_amdgcn_s_setprio(0);

    // prologue: tile 0 pieces in order; vmcnt(4) lands A0,B0
    STAGE(0,0); STAGE(0,1); STAGE(0,2); STAGE(0,3);
    VMC(4);
    SBAR();

    for (int T = 0; T < NTG; ++T){
        const char* cb = lds + (T & 1)*65536;
        const bool hn = (T + 1 < NTG);

        // ---- ph0: Q00 ----
        LOAD_A(cb);                    // A0
        LOAD_B(cb + 32768, bB0);       // B0
        if (hn) STAGE(T+1, 0);
        if (hn) { VMC(4); } else { VMC(2); }
        SBAR();
        LGKM0();
        MFMA16(acc0, bB0);
        SBAR();

        // ---- ph1: Q01 ----
        LOAD_B(cb + 49152, bB1);       // B1
        if (hn) STAGE(T+1, 1);
        if (hn) { VMC(4); } else { VMC(0); }
        SBAR();
        LGKM0();
        MFMA16(acc1, bB1);
        SBAR();

        // ---- ph2: Q11 ----
        LOAD_A(cb + 16384);            // A1
        if (hn) STAGE(T+1, 2);
        if (hn) { VMC(4); }
        SBAR();
        LGKM0();
        MFMA16(acc3, bB1);
        SBAR();

        // ---- ph3: Q10 (all operands in regs) ----
        if (hn) STAGE(T+1, 3);
        if (hn) { VMC(4); }
        SBAR();
        MFMA16(acc2, bB0);
        SBAR();
    }

    // ---- epilogue: sigmoid(gate)*value -> padded LDS transpose -> store ----
    __syncthreads();
    unsigned short* ep = reinterpret_cast<unsigned short*>(lds);  // [256][LDSE]
    #pragma unroll
    for (int q = 0; q < 4; ++q){
        const f32x4* ac = (q==0) ? acc0 : (q==1) ? acc1 : (q==2) ? acc2 : acc3;
        const int QM = q >> 1, QN = q & 1;
        const int el = QN*64 + wqn*16 + fr;            // 0..127
        const float rbe = rbias[nt*128 + el];
        const float vbe = vbias[nt*128 + el];
        #pragma unroll
        for (int rf = 0; rf < 4; ++rf){
            const int rbase = QM*128 + wqm*64 + rf*16 + fq*4;
            f32x4 ga = ac[rf*2+0], va = ac[rf*2+1];
            #pragma unroll
            for (int qq = 0; qq < 4; ++qq){
                const float g = sigmoidf_fast(ga[qq] + rbe);
                ep[(rbase + qq)*LDSE + el] = f2bf(g*(va[qq] + vbe));
            }
        }
    }
    __syncthreads();
    #pragma unroll
    for (int p = 0; p < 8; ++p){
        const int r  = p*32 + (tid >> 4);
        const int c8 = tid & 15;
        shortx8 val = *reinterpret_cast<const shortx8*>(&ep[r*LDSE + c8*8]);
        *reinterpret_cast<shortx8*>(&gv[(size_t)(m0 + r)*DIM + nt*128 + c8*8]) = val;
    }
    #undef MFMA16
}

// ---------------- K6: LN2 + residual (wave-per-row) ----------------
__global__ __launch_bounds__(256) void k_ln2_res(
    const unsigned short* __restrict__ gvb, const unsigned short* __restrict__ shifted,
    const float* __restrict__ g2, const float* __restrict__ b2,
    float* __restrict__ out)
{
    const int tid = threadIdx.x, lane = tid & 63, wid = tid >> 6;
    const int row = blockIdx.x*4 + wid;

    const shortx4* GV = reinterpret_cast<const shortx4*>(gvb) + (size_t)row*256;
    const shortx4* SH = reinterpret_cast<const shortx4*>(shifted) + (size_t)row*256;

    f32x4 v[4];
    float s = 0.f, s2 = 0.f;
    #pragma unroll
    for (int j = 0; j < 4; ++j){
        f32x4 x = unpack4(GV[j*64 + lane]);
        v[j] = x;
        s  += x.x+x.y+x.z+x.w;
        s2 += x.x*x.x + x.y*x.y + x.z*x.z + x.w*x.w;
    }
    #pragma unroll
    for (int off = 1; off < 64; off <<= 1){
        s  += __shfl_xor(s,  off, 64);
        s2 += __shfl_xor(s2, off, 64);
    }
    const float mean = s * (1.0f/DIM);
    const float rstd = rsqrtf(s2*(1.0f/DIM) - mean*mean + 1e-5f);
    f32x4* O = reinterpret_cast<f32x4*>(out) + (size_t)row*256;
    #pragma unroll
    for (int j = 0; j < 4; ++j){
        f32x4 gg = reinterpret_cast<const f32x4*>(g2)[j*64 + lane];
        f32x4 bb = reinterpret_cast<const f32x4*>(b2)[j*64 + lane];
        f32x4 sh = unpack4(SH[j*64 + lane]);
        O[j*64 + lane] = sh + (v[j] - mean)*rstd*gg + bb;
    }
}

extern "C" void kernel_launch(void* const* d_in, const int* in_sizes, int n_in,
                              void* d_out, int out_size, void* d_ws, size_t ws_size,
                              hipStream_t stream)
{
    (void)in_sizes; (void)n_in; (void)out_size; (void)ws_size;
    const float* x     = (const float*)d_in[0];
    const float* xprev = (const float*)d_in[1];
    const float* mu    = (const float*)d_in[2];
    const float* dw    = (const float*)d_in[3];
    const float* db    = (const float*)d_in[4];
    const float* ln1g  = (const float*)d_in[5];
    const float* ln1b  = (const float*)d_in[6];
    const float* Wr    = (const float*)d_in[7];
    const float* Wrb   = (const float*)d_in[8];
    const float* Wv    = (const float*)d_in[9];
    const float* Wvb   = (const float*)d_in[10];
    const float* ln2g  = (const float*)d_in[11];
    const float* ln2b  = (const float*)d_in[12];
    float* out = (float*)d_out;

    char* ws = (char*)d_ws;
    size_t off = 0;
    auto alloc = [&](size_t bytes) -> void* {
        void* p = ws + off;
        off += (bytes + 255) & ~(size_t)255;
        return p;
    };
    unsigned short* shifted = (unsigned short*)alloc((size_t)NROWS*DIM*2);
    unsigned short* b_local = (unsigned short*)alloc((size_t)NROWS*DIM*2);
    unsigned short* merged  = (unsigned short*)alloc((size_t)NROWS*DIM*2);
    unsigned short* carryB  = (unsigned short*)alloc((size_t)BATCH*NCH*DIM*2);
    unsigned short* Wcat    = (unsigned short*)alloc((size_t)2048*1024*2);
    float* a_local          = (float*)alloc((size_t)NROWS*4);
    float* cumP             = (float*)alloc((size_t)NROWS*4);
    float* carryA           = (float*)alloc((size_t)BATCH*NCH*4);
    unsigned short* gvbuf   = b_local;   // b_local dead after k_fix_ln1

    hipLaunchKernelGGL(k_shift_scan, dim3(576),  dim3(256), 0, stream,
                       x, xprev, mu, dw, db, Wr, Wv, Wcat, shifted, b_local, a_local, cumP);
    hipLaunchKernelGGL(k_combine,    dim3(16),   dim3(64),  0, stream,
                       b_local, a_local, cumP, carryA, carryB);
    hipLaunchKernelGGL(k_fix_ln1,    dim3(4096), dim3(256), 0, stream,
                       b_local, a_local, cumP, carryA, carryB, ln1g, ln1b, merged);
    hipLaunchKernelGGL(k_gemm,       dim3(512),  dim3(512), 0, stream,
                       merged, Wcat, Wrb, Wvb, gvbuf);
    hipLaunchKernelGGL(k_ln2_res,    dim3(4096), dim3(256), 0, stream,
                       gvbuf, shifted, ln2g, ln2b, out);
}